// Round 1
// baseline (1952.463 us; speedup 1.0000x reference)
//
#include <hip/hip_runtime.h>
#include <hip/hip_bf16.h>
#include <cstdint>
#include <cstddef>

#define HIDDEN_ 4096
#define NHEAD 32
#define HDIM 128
#define SEQ 2048
#define BATCH 2
#define MROWS (BATCH * SEQ)      // 4096
#define QKVN (3 * HIDDEN_)       // 12288

typedef __bf16 bf16;
typedef __bf16 bf16x8 __attribute__((ext_vector_type(8)));
typedef float f32x4 __attribute__((ext_vector_type(4)));

// ---------------- cast fp32 -> bf16, 8 elems/thread ----------------
__global__ __launch_bounds__(256) void cast_bf16_k(const float* __restrict__ in,
                                                   bf16* __restrict__ out, int n) {
  int i = (blockIdx.x * 256 + threadIdx.x) * 8;
  if (i >= n) return;
  f32x4 a = *(const f32x4*)(in + i);
  f32x4 b = *(const f32x4*)(in + i + 4);
  bf16x8 o;
  o[0] = (bf16)a[0]; o[1] = (bf16)a[1]; o[2] = (bf16)a[2]; o[3] = (bf16)a[3];
  o[4] = (bf16)b[0]; o[5] = (bf16)b[1]; o[6] = (bf16)b[2]; o[7] = (bf16)b[3];
  *(bf16x8*)(out + i) = o;
}

// ---------------- transpose + cast: in[R][C] fp32 -> out[C][R] bf16 ----------------
__global__ __launch_bounds__(256) void transpose_cast_k(const float* __restrict__ in,
                                                        bf16* __restrict__ out,
                                                        int R, int C) {
  __shared__ float tile[32][33];
  int c0 = blockIdx.x * 32, r0 = blockIdx.y * 32;
  int tx = threadIdx.x & 31, ty = threadIdx.x >> 5;  // 32 x 8
#pragma unroll
  for (int i = 0; i < 4; i++) {
    int r = ty + i * 8;
    tile[r][tx] = in[(size_t)(r0 + r) * C + (c0 + tx)];
  }
  __syncthreads();
#pragma unroll
  for (int i = 0; i < 4; i++) {
    int r = ty + i * 8;
    out[(size_t)(c0 + r) * R + (r0 + tx)] = (bf16)tile[tx][r];
  }
}

// ---------------- GEMM: A[M][K] bf16 x BT[N][K] bf16 -> C[M][N] ----------------
// EPI=0: scatter into Q[B,H,S,D], K[B,H,S,D], Vt[B,H,D,S] (bf16) with bias.
// EPI=1: plain fp32 [M][N] with bias.
template <int EPI>
__global__ __launch_bounds__(256) void gemm_bt_k(
    const bf16* __restrict__ A, const bf16* __restrict__ BT,
    const float* __restrict__ bias, float* __restrict__ outF,
    bf16* __restrict__ Qb, bf16* __restrict__ Kb, bf16* __restrict__ Vt,
    int M, int N, int K) {
  __shared__ bf16 As[128 * 32];
  __shared__ bf16 Bs[128 * 32];
  const int m0 = blockIdx.y * 128, n0 = blockIdx.x * 128;
  const int tid = threadIdx.x;
  const int w = tid >> 6, l = tid & 63;
  const int wm = (w >> 1) * 64, wn = (w & 1) * 64;  // wave's 64x64 quadrant
  const int lg = l >> 4, cl = l & 15;
  f32x4 acc[4][4] = {};

  const int srow = l >> 2;       // row within a 16-row staging chunk
  const int scol = (l & 3) * 8;  // 8-elem column group

  for (int k0 = 0; k0 < K; k0 += 32) {
#pragma unroll
    for (int i = 0; i < 2; i++) {
      int c = w * 2 + i;  // chunk 0..7 (each = 1024B = 16 rows x 32 cols)
      const bf16* ga = A + (size_t)(m0 + c * 16 + srow) * K + (k0 + scol);
      const bf16* gb = BT + (size_t)(n0 + c * 16 + srow) * K + (k0 + scol);
      __builtin_amdgcn_global_load_lds((const __attribute__((address_space(1))) void*)ga,
                                       (__attribute__((address_space(3))) void*)&As[c * 512],
                                       16, 0, 0);
      __builtin_amdgcn_global_load_lds((const __attribute__((address_space(1))) void*)gb,
                                       (__attribute__((address_space(3))) void*)&Bs[c * 512],
                                       16, 0, 0);
    }
    __syncthreads();
    bf16x8 af[4], bfr[4];
#pragma unroll
    for (int i = 0; i < 4; i++)
      af[i] = *(const bf16x8*)&As[(wm + i * 16 + cl) * 32 + lg * 8];
#pragma unroll
    for (int j = 0; j < 4; j++)
      bfr[j] = *(const bf16x8*)&Bs[(wn + j * 16 + cl) * 32 + lg * 8];
#pragma unroll
    for (int i = 0; i < 4; i++)
#pragma unroll
      for (int j = 0; j < 4; j++)
        acc[i][j] = __builtin_amdgcn_mfma_f32_16x16x32_bf16(af[i], bfr[j], acc[i][j], 0, 0, 0);
    __syncthreads();
  }

#pragma unroll
  for (int i = 0; i < 4; i++) {
#pragma unroll
    for (int j = 0; j < 4; j++) {
      int col = n0 + wn + j * 16 + cl;
      float bv = bias[col];
#pragma unroll
      for (int r = 0; r < 4; r++) {
        int row = m0 + wm + i * 16 + lg * 4 + r;
        float v = acc[i][j][r] + bv;
        if (EPI == 0) {
          int which = col >> 12, rem = col & 4095;
          int h = rem >> 7, d = rem & 127;
          int b = row >> 11, s = row & 2047;
          size_t bh = (size_t)b * NHEAD + h;
          if (which == 0)      Qb[(bh * SEQ + s) * HDIM + d] = (bf16)v;
          else if (which == 1) Kb[(bh * SEQ + s) * HDIM + d] = (bf16)v;
          else                 Vt[(bh * HDIM + d) * SEQ + s] = (bf16)v;
        } else {
          outF[(size_t)row * N + col] = v;
        }
      }
    }
  }
}

// ---------------- flash attention with ALiBi + causal ----------------
// grid = B*H*(S/64); 4 waves/block, each wave owns 16 q-rows independently.
__global__ __launch_bounds__(256) void attn_k(const bf16* __restrict__ Qb,
                                              const bf16* __restrict__ Kb,
                                              const bf16* __restrict__ Vt,
                                              bf16* __restrict__ ctx) {
  __shared__ bf16 Pl[4][16 * 80];  // per-wave P tile [16 q][64 kv], stride 80 (bank spread)
  const int tid = threadIdx.x, w = tid >> 6, l = tid & 63;
  const int bid = blockIdx.x;
  const int qt = bid & 31, bh = bid >> 5;
  const int h = bh & (NHEAD - 1), b = bh >> 5;
  const int qbase = qt * 64 + w * 16;
  const float slope = exp2f(-0.25f * (float)(h + 1));  // JAIS ALiBi, 32 heads
  const float scale = 1.0f / 128.0f;                   // 1/d, not 1/sqrt(d)
  const int lg = l >> 4, cl = l & 15;

  const bf16* Qp = Qb + (size_t)bh * SEQ * HDIM;
  const bf16* Kp = Kb + (size_t)bh * SEQ * HDIM;
  const bf16* Vp = Vt + (size_t)bh * HDIM * SEQ;
  bf16* pl = &Pl[w][0];

  // Q fragments: A[m=cl][k = kb*32 + lg*8 + e]
  bf16x8 qf[4];
#pragma unroll
  for (int kb = 0; kb < 4; kb++)
    qf[kb] = *(const bf16x8*)&Qp[(size_t)(qbase + cl) * HDIM + kb * 32 + lg * 8];

  float mi[4], li[4];
#pragma unroll
  for (int r = 0; r < 4; r++) { mi[r] = -3.0e38f; li[r] = 0.0f; }
  f32x4 oacc[8] = {};

  for (int kv0 = 0; kv0 <= qbase + 15; kv0 += 64) {
    // ---- S = Q K^T over this 16x64 strip ----
    f32x4 sacc[4];
#pragma unroll
    for (int nb = 0; nb < 4; nb++) {
      f32x4 a = {};
#pragma unroll
      for (int kb = 0; kb < 4; kb++) {
        bf16x8 kf = *(const bf16x8*)&Kp[(size_t)(kv0 + nb * 16 + cl) * HDIM + kb * 32 + lg * 8];
        a = __builtin_amdgcn_mfma_f32_16x16x32_bf16(qf[kb], kf, a, 0, 0, 0);
      }
      sacc[nb] = a;
    }
    // ---- scale + ALiBi + causal mask, row max ----
    float pm[4], sv[4][4];
#pragma unroll
    for (int r = 0; r < 4; r++) pm[r] = -3.0e38f;
#pragma unroll
    for (int nb = 0; nb < 4; nb++) {
      int kv = kv0 + nb * 16 + cl;
#pragma unroll
      for (int r = 0; r < 4; r++) {
        int q = qbase + lg * 4 + r;
        float v = sacc[nb][r] * scale + slope * (float)(kv - q);
        v = (kv <= q) ? v : -3.0e38f;
        sv[nb][r] = v;
        pm[r] = fmaxf(pm[r], v);
      }
    }
#pragma unroll
    for (int r = 0; r < 4; r++) {
      pm[r] = fmaxf(pm[r], __shfl_xor(pm[r], 1));
      pm[r] = fmaxf(pm[r], __shfl_xor(pm[r], 2));
      pm[r] = fmaxf(pm[r], __shfl_xor(pm[r], 4));
      pm[r] = fmaxf(pm[r], __shfl_xor(pm[r], 8));
    }
    // ---- online softmax update ----
    float alpha[4], rs[4];
#pragma unroll
    for (int r = 0; r < 4; r++) {
      float nm = fmaxf(mi[r], pm[r]);
      alpha[r] = __expf(mi[r] - nm);
      mi[r] = nm;
      rs[r] = 0.0f;
    }
#pragma unroll
    for (int nb = 0; nb < 4; nb++) {
#pragma unroll
      for (int r = 0; r < 4; r++) {
        float p = __expf(sv[nb][r] - mi[r]);  // masked -> exp(-huge) = 0
        rs[r] += p;
        pl[(lg * 4 + r) * 80 + nb * 16 + cl] = (bf16)p;
      }
    }
#pragma unroll
    for (int r = 0; r < 4; r++) {
      rs[r] += __shfl_xor(rs[r], 1);
      rs[r] += __shfl_xor(rs[r], 2);
      rs[r] += __shfl_xor(rs[r], 4);
      rs[r] += __shfl_xor(rs[r], 8);
      li[r] = li[r] * alpha[r] + rs[r];
    }
#pragma unroll
    for (int db = 0; db < 8; db++)
#pragma unroll
      for (int r = 0; r < 4; r++) oacc[db][r] *= alpha[r];
    // ---- PV: A = P[q][kv] from LDS, B = Vt[d][kv] ----
    bf16x8 pa[2];
#pragma unroll
    for (int ks = 0; ks < 2; ks++)
      pa[ks] = *(const bf16x8*)&pl[cl * 80 + ks * 32 + lg * 8];
#pragma unroll
    for (int db = 0; db < 8; db++) {
      f32x4 o = oacc[db];
#pragma unroll
      for (int ks = 0; ks < 2; ks++) {
        bf16x8 vf = *(const bf16x8*)&Vp[(size_t)(db * 16 + cl) * SEQ + kv0 + ks * 32 + lg * 8];
        o = __builtin_amdgcn_mfma_f32_16x16x32_bf16(pa[ks], vf, o, 0, 0, 0);
      }
      oacc[db] = o;
    }
  }
  // ---- normalize + write ctx[b, q, h*128 + d] ----
#pragma unroll
  for (int db = 0; db < 8; db++) {
#pragma unroll
    for (int r = 0; r < 4; r++) {
      int q = qbase + lg * 4 + r;
      float val = oacc[db][r] / li[r];
      ctx[((size_t)(b * SEQ + q)) * HIDDEN_ + h * HDIM + db * 16 + cl] = (bf16)val;
    }
  }
}

// ---------------- launcher ----------------
extern "C" void kernel_launch(void* const* d_in, const int* in_sizes, int n_in,
                              void* d_out, int out_size, void* d_ws, size_t ws_size,
                              hipStream_t stream) {
  const float* hs     = (const float*)d_in[0];
  const float* w_attn = (const float*)d_in[1];
  const float* b_attn = (const float*)d_in[2];
  const float* w_proj = (const float*)d_in[3];
  const float* b_proj = (const float*)d_in[4];
  float* out = (float*)d_out;

  char* ws = (char*)d_ws;
  bf16* Xb  = (bf16*)(ws + 0);           // [4096][4096]        33.5 MB
  bf16* WaT = (bf16*)(ws + 33554432);    // [12288][4096]      100.7 MB
  bf16* WpT = (bf16*)(ws + 134217728);   // [4096][4096]        33.5 MB
  bf16* Qb  = (bf16*)(ws + 167772160);   // [B,H,S,D]           33.5 MB
  bf16* Kb  = (bf16*)(ws + 201326592);   // [B,H,S,D]           33.5 MB
  bf16* Vt  = (bf16*)(ws + 234881024);   // [B,H,D,S]           33.5 MB
  bf16* ctx = (bf16*)(ws + 268435456);   // [4096][4096]        33.5 MB

  cast_bf16_k<<<(MROWS * HIDDEN_) / (256 * 8), 256, 0, stream>>>(hs, Xb, MROWS * HIDDEN_);
  transpose_cast_k<<<dim3(QKVN / 32, HIDDEN_ / 32), 256, 0, stream>>>(w_attn, WaT, HIDDEN_, QKVN);
  transpose_cast_k<<<dim3(HIDDEN_ / 32, HIDDEN_ / 32), 256, 0, stream>>>(w_proj, WpT, HIDDEN_, HIDDEN_);

  gemm_bt_k<0><<<dim3(QKVN / 128, MROWS / 128), 256, 0, stream>>>(
      Xb, WaT, b_attn, nullptr, Qb, Kb, Vt, MROWS, QKVN, HIDDEN_);

  attn_k<<<BATCH * NHEAD * (SEQ / 64), 256, 0, stream>>>(Qb, Kb, Vt, ctx);

  gemm_bt_k<1><<<dim3(HIDDEN_ / 128, MROWS / 128), 256, 0, stream>>>(
      ctx, WpT, b_proj, out, nullptr, nullptr, nullptr, MROWS, HIDDEN_, HIDDEN_);
}

// Round 2
// 1210.881 us; speedup vs baseline: 1.6124x; 1.6124x over previous
//
#include <hip/hip_runtime.h>
#include <hip/hip_bf16.h>
#include <cstdint>
#include <cstddef>

#define HIDDEN_ 4096
#define NHEAD 32
#define HDIM 128
#define SEQ 2048
#define BATCH 2
#define MROWS (BATCH * SEQ)      // 4096
#define QKVN (3 * HIDDEN_)       // 12288

typedef __bf16 bf16;
typedef __bf16 bf16x8 __attribute__((ext_vector_type(8)));
typedef float f32x4 __attribute__((ext_vector_type(4)));

// ---------------- cast fp32 -> bf16, 8 elems/thread ----------------
__global__ __launch_bounds__(256) void cast_bf16_k(const float* __restrict__ in,
                                                   bf16* __restrict__ out, int n) {
  int i = (blockIdx.x * 256 + threadIdx.x) * 8;
  if (i >= n) return;
  f32x4 a = *(const f32x4*)(in + i);
  f32x4 b = *(const f32x4*)(in + i + 4);
  bf16x8 o;
  o[0] = (bf16)a[0]; o[1] = (bf16)a[1]; o[2] = (bf16)a[2]; o[3] = (bf16)a[3];
  o[4] = (bf16)b[0]; o[5] = (bf16)b[1]; o[6] = (bf16)b[2]; o[7] = (bf16)b[3];
  *(bf16x8*)(out + i) = o;
}

// ---------------- transpose + cast: in[R][C] fp32 -> out[C][R] bf16 ----------------
__global__ __launch_bounds__(256) void transpose_cast_k(const float* __restrict__ in,
                                                        bf16* __restrict__ out,
                                                        int R, int C) {
  __shared__ float tile[32][33];
  int c0 = blockIdx.x * 32, r0 = blockIdx.y * 32;
  int tx = threadIdx.x & 31, ty = threadIdx.x >> 5;  // 32 x 8
#pragma unroll
  for (int i = 0; i < 4; i++) {
    int r = ty + i * 8;
    tile[r][tx] = in[(size_t)(r0 + r) * C + (c0 + tx)];
  }
  __syncthreads();
#pragma unroll
  for (int i = 0; i < 4; i++) {
    int r = ty + i * 8;
    out[(size_t)(c0 + r) * R + (r0 + tx)] = (bf16)tile[tx][r];
  }
}

// ---------------- GEMM: A[M][K] bf16 x BT[N][K] bf16 -> C[M][N] ----------------
// EPI=0: scatter into Q[B,H,S,D], K[B,H,S,D], Vt[B,H,D,S] (bf16) with bias.
// EPI=1: plain fp32 [M][N] with bias.
template <int EPI>
__global__ __launch_bounds__(256) void gemm_bt_k(
    const bf16* __restrict__ A, const bf16* __restrict__ BT,
    const float* __restrict__ bias, float* __restrict__ outF,
    bf16* __restrict__ Qb, bf16* __restrict__ Kb, bf16* __restrict__ Vt,
    int M, int N, int K) {
  __shared__ bf16 As[128 * 32];
  __shared__ bf16 Bs[128 * 32];
  const int m0 = blockIdx.y * 128, n0 = blockIdx.x * 128;
  const int tid = threadIdx.x;
  const int w = tid >> 6, l = tid & 63;
  const int wm = (w >> 1) * 64, wn = (w & 1) * 64;  // wave's 64x64 quadrant
  const int lg = l >> 4, cl = l & 15;
  f32x4 acc[4][4] = {};

  const int srow = l >> 2;       // row within a 16-row staging chunk
  const int scol = (l & 3) * 8;  // 8-elem column group

  for (int k0 = 0; k0 < K; k0 += 32) {
#pragma unroll
    for (int i = 0; i < 2; i++) {
      int c = w * 2 + i;  // chunk 0..7 (each = 1024B = 16 rows x 32 cols)
      const bf16* ga = A + (size_t)(m0 + c * 16 + srow) * K + (k0 + scol);
      const bf16* gb = BT + (size_t)(n0 + c * 16 + srow) * K + (k0 + scol);
      __builtin_amdgcn_global_load_lds((const __attribute__((address_space(1))) void*)ga,
                                       (__attribute__((address_space(3))) void*)&As[c * 512],
                                       16, 0, 0);
      __builtin_amdgcn_global_load_lds((const __attribute__((address_space(1))) void*)gb,
                                       (__attribute__((address_space(3))) void*)&Bs[c * 512],
                                       16, 0, 0);
    }
    __syncthreads();
    bf16x8 af[4], bfr[4];
#pragma unroll
    for (int i = 0; i < 4; i++)
      af[i] = *(const bf16x8*)&As[(wm + i * 16 + cl) * 32 + lg * 8];
#pragma unroll
    for (int j = 0; j < 4; j++)
      bfr[j] = *(const bf16x8*)&Bs[(wn + j * 16 + cl) * 32 + lg * 8];
#pragma unroll
    for (int i = 0; i < 4; i++)
#pragma unroll
      for (int j = 0; j < 4; j++)
        acc[i][j] = __builtin_amdgcn_mfma_f32_16x16x32_bf16(af[i], bfr[j], acc[i][j], 0, 0, 0);
    __syncthreads();
  }

#pragma unroll
  for (int i = 0; i < 4; i++) {
#pragma unroll
    for (int j = 0; j < 4; j++) {
      int col = n0 + wn + j * 16 + cl;
      float bv = bias[col];
#pragma unroll
      for (int r = 0; r < 4; r++) {
        int row = m0 + wm + i * 16 + lg * 4 + r;
        float v = acc[i][j][r] + bv;
        if (EPI == 0) {
          int which = col >> 12, rem = col & 4095;
          int h = rem >> 7, d = rem & 127;
          int b = row >> 11, s = row & 2047;
          size_t bh = (size_t)b * NHEAD + h;
          if (which == 0)      Qb[(bh * SEQ + s) * HDIM + d] = (bf16)v;
          else if (which == 1) Kb[(bh * SEQ + s) * HDIM + d] = (bf16)v;
          else                 Vt[(bh * HDIM + d) * SEQ + s] = (bf16)v;
        } else {
          outF[(size_t)row * N + col] = v;
        }
      }
    }
  }
}

// ---------------- flash attention v2: LDS-staged, double-buffered, swizzled ----------------
// grid = 16 qsteps * 64 bh, LONGEST-FIRST (qt = 15 - qstep).
// 512 threads = 8 waves; wave w owns 16 q-rows (qbase = qt*128 + w*16).
// K tile [64][128] and V tile [128][64] staged via global_load_lds with XOR
// swizzle (byte ^= (row&7)<<4) applied by pre-swizzling the GLOBAL source
// address (linear LDS dest) and swizzling the ds_read address (rule 21).
__global__ __launch_bounds__(512, 2) void attn_k(const bf16* __restrict__ Qb,
                                                 const bf16* __restrict__ Kb,
                                                 const bf16* __restrict__ Vt,
                                                 bf16* __restrict__ ctx) {
  __shared__ bf16 Ks[2][64 * 128];   // 2 x 16 KB
  __shared__ bf16 Vs[2][128 * 64];   // 2 x 16 KB
  __shared__ bf16 Pl[8][16 * 64];    // 16 KB, per-wave P tile (swizzled)
  const int tid = threadIdx.x, w = tid >> 6, l = tid & 63;
  const int bid = blockIdx.x;
  const int qt = 15 - (bid >> 6);          // longest blocks first
  const int bh = bid & 63;
  const int h = bh & (NHEAD - 1), b = bh >> 5;
  const int qbase = qt * 128 + w * 16;
  const int nt = 2 * qt + 2;               // KV tiles of 64 covering rows < qt*128+128
  const float slope = exp2f(-0.25f * (float)(h + 1));
  const float scale = 1.0f / 128.0f;
  const int lg = l >> 4, cl = l & 15;

  const bf16* Qp = Qb + (size_t)bh * SEQ * HDIM;
  const bf16* Kp = Kb + (size_t)bh * SEQ * HDIM;
  const bf16* Vp = Vt + (size_t)bh * HDIM * SEQ;
  char* plb = (char*)&Pl[w][0];

  // Q fragments: A[m=cl][k=kb*32+lg*8+e], loaded once
  bf16x8 qf[4];
#pragma unroll
  for (int kb = 0; kb < 4; kb++)
    qf[kb] = *(const bf16x8*)&Qp[(size_t)(qbase + cl) * HDIM + kb * 32 + lg * 8];

  float mi[4], li[4];
#pragma unroll
  for (int r = 0; r < 4; r++) { mi[r] = -3.0e38f; li[r] = 0.0f; }
  f32x4 oacc[8] = {};

  // --- staging: 32 KB/tile = 2048 x 16B chunks; 512 threads x (2 K + 2 V) ---
  auto stage = [&](int buf, int t) {
    const int kv0 = t * 64;
#pragma unroll
    for (int i = 0; i < 2; i++) {
      const int ci = i * 512 + tid;  // chunk index 0..1023
      {  // K: phys row = ci>>4 (256B rows), logical col byte = phys ^ swz
        const int r = ci >> 4;
        const int cbl = ((ci & 15) << 4) ^ ((r & 7) << 4);
        const bf16* src = Kp + (size_t)(kv0 + r) * HDIM + (cbl >> 1);
        __builtin_amdgcn_global_load_lds(
            (const __attribute__((address_space(1))) void*)src,
            (__attribute__((address_space(3))) void*)((char*)&Ks[buf][0] + ci * 16), 16, 0, 0);
      }
      {  // V: phys row = ci>>3 (128B rows)
        const int r = ci >> 3;
        const int cbl = ((ci & 7) << 4) ^ ((r & 7) << 4);
        const bf16* src = Vp + (size_t)r * SEQ + kv0 + (cbl >> 1);
        __builtin_amdgcn_global_load_lds(
            (const __attribute__((address_space(1))) void*)src,
            (__attribute__((address_space(3))) void*)((char*)&Vs[buf][0] + ci * 16), 16, 0, 0);
      }
    }
  };

  stage(0, 0);
  __syncthreads();  // implicit vmcnt(0) drain -> tile 0 resident

  for (int t = 0; t < nt; ++t) {
    const int cur = t & 1;
    if (t + 1 < nt) stage(cur ^ 1, t + 1);  // async prefetch under compute
    const int kv0 = t * 64;

    if (kv0 <= qbase + 15) {  // wave-uniform: skip fully-masked tiles
      char* ksb = (char*)&Ks[cur][0];
      char* vsb = (char*)&Vs[cur][0];
      // ---- S = Q K^T (16x64) from swizzled LDS ----
      f32x4 sacc[4];
#pragma unroll
      for (int nb = 0; nb < 4; nb++) {
        f32x4 a = {};
#pragma unroll
        for (int kb = 0; kb < 4; kb++) {
          const int row = nb * 16 + cl;
          const int cb = (kb * 64 + lg * 16) ^ ((row & 7) << 4);
          bf16x8 kf = *(const bf16x8*)(ksb + row * 256 + cb);
          a = __builtin_amdgcn_mfma_f32_16x16x32_bf16(qf[kb], kf, a, 0, 0, 0);
        }
        sacc[nb] = a;
      }
      // ---- scale + ALiBi + causal, row max ----
      float pm[4], sv[4][4];
#pragma unroll
      for (int r = 0; r < 4; r++) pm[r] = -3.0e38f;
#pragma unroll
      for (int nb = 0; nb < 4; nb++) {
        const int kv = kv0 + nb * 16 + cl;
#pragma unroll
        for (int r = 0; r < 4; r++) {
          const int q = qbase + lg * 4 + r;
          float v = sacc[nb][r] * scale + slope * (float)(kv - q);
          v = (kv <= q) ? v : -3.0e38f;
          sv[nb][r] = v;
          pm[r] = fmaxf(pm[r], v);
        }
      }
#pragma unroll
      for (int r = 0; r < 4; r++) {
        pm[r] = fmaxf(pm[r], __shfl_xor(pm[r], 1));
        pm[r] = fmaxf(pm[r], __shfl_xor(pm[r], 2));
        pm[r] = fmaxf(pm[r], __shfl_xor(pm[r], 4));
        pm[r] = fmaxf(pm[r], __shfl_xor(pm[r], 8));
      }
      // ---- online softmax update; P -> swizzled per-wave LDS ----
      float alpha[4], rs[4];
#pragma unroll
      for (int r = 0; r < 4; r++) {
        const float nm = fmaxf(mi[r], pm[r]);
        alpha[r] = __expf(mi[r] - nm);
        mi[r] = nm;
        rs[r] = 0.0f;
      }
#pragma unroll
      for (int nb = 0; nb < 4; nb++) {
#pragma unroll
        for (int r = 0; r < 4; r++) {
          const float p = __expf(sv[nb][r] - mi[r]);
          rs[r] += p;
          const int row = lg * 4 + r;
          *(bf16*)(plb + row * 128 + ((((nb * 16 + cl) << 1)) ^ ((row & 7) << 4))) = (bf16)p;
        }
      }
#pragma unroll
      for (int r = 0; r < 4; r++) {
        rs[r] += __shfl_xor(rs[r], 1);
        rs[r] += __shfl_xor(rs[r], 2);
        rs[r] += __shfl_xor(rs[r], 4);
        rs[r] += __shfl_xor(rs[r], 8);
        li[r] = li[r] * alpha[r] + rs[r];
      }
#pragma unroll
      for (int db = 0; db < 8; db++)
#pragma unroll
        for (int r = 0; r < 4; r++) oacc[db][r] *= alpha[r];
      // ---- PV: A = P (swizzled LDS), B = V tile (swizzled LDS) ----
      bf16x8 pa[2];
#pragma unroll
      for (int ks = 0; ks < 2; ks++) {
        const int cb = (ks * 64 + lg * 16) ^ ((cl & 7) << 4);
        pa[ks] = *(const bf16x8*)(plb + cl * 128 + cb);
      }
#pragma unroll
      for (int db = 0; db < 8; db++) {
        f32x4 o = oacc[db];
#pragma unroll
        for (int ks = 0; ks < 2; ks++) {
          const int row = db * 16 + cl;
          const int cb = (ks * 64 + lg * 16) ^ ((row & 7) << 4);
          bf16x8 vf = *(const bf16x8*)(vsb + row * 128 + cb);
          o = __builtin_amdgcn_mfma_f32_16x16x32_bf16(pa[ks], vf, o, 0, 0, 0);
        }
        oacc[db] = o;
      }
    }
    __syncthreads();  // drains prefetch vmcnt + protects buffer swap
  }

  // ---- normalize + write ctx[b, q, h*128 + d] ----
  float inv[4];
#pragma unroll
  for (int r = 0; r < 4; r++) inv[r] = 1.0f / li[r];
#pragma unroll
  for (int db = 0; db < 8; db++) {
#pragma unroll
    for (int r = 0; r < 4; r++) {
      const int q = qbase + lg * 4 + r;
      ctx[((size_t)(b * SEQ + q)) * HIDDEN_ + h * HDIM + db * 16 + cl] = (bf16)(oacc[db][r] * inv[r]);
    }
  }
}

// ---------------- launcher ----------------
extern "C" void kernel_launch(void* const* d_in, const int* in_sizes, int n_in,
                              void* d_out, int out_size, void* d_ws, size_t ws_size,
                              hipStream_t stream) {
  const float* hs     = (const float*)d_in[0];
  const float* w_attn = (const float*)d_in[1];
  const float* b_attn = (const float*)d_in[2];
  const float* w_proj = (const float*)d_in[3];
  const float* b_proj = (const float*)d_in[4];
  float* out = (float*)d_out;

  char* ws = (char*)d_ws;
  bf16* Xb  = (bf16*)(ws + 0);           // [4096][4096]        33.5 MB
  bf16* WaT = (bf16*)(ws + 33554432);    // [12288][4096]      100.7 MB
  bf16* WpT = (bf16*)(ws + 134217728);   // [4096][4096]        33.5 MB
  bf16* Qb  = (bf16*)(ws + 167772160);   // [B,H,S,D]           33.5 MB
  bf16* Kb  = (bf16*)(ws + 201326592);   // [B,H,S,D]           33.5 MB
  bf16* Vt  = (bf16*)(ws + 234881024);   // [B,H,D,S]           33.5 MB
  bf16* ctx = (bf16*)(ws + 268435456);   // [4096][4096]        33.5 MB

  cast_bf16_k<<<(MROWS * HIDDEN_) / (256 * 8), 256, 0, stream>>>(hs, Xb, MROWS * HIDDEN_);
  transpose_cast_k<<<dim3(QKVN / 32, HIDDEN_ / 32), 256, 0, stream>>>(w_attn, WaT, HIDDEN_, QKVN);
  transpose_cast_k<<<dim3(HIDDEN_ / 32, HIDDEN_ / 32), 256, 0, stream>>>(w_proj, WpT, HIDDEN_, HIDDEN_);

  gemm_bt_k<0><<<dim3(QKVN / 128, MROWS / 128), 256, 0, stream>>>(
      Xb, WaT, b_attn, nullptr, Qb, Kb, Vt, MROWS, QKVN, HIDDEN_);

  attn_k<<<16 * 64, 512, 0, stream>>>(Qb, Kb, Vt, ctx);

  gemm_bt_k<1><<<dim3(HIDDEN_ / 128, MROWS / 128), 256, 0, stream>>>(
      ctx, WpT, b_proj, out, nullptr, nullptr, nullptr, MROWS, HIDDEN_, HIDDEN_);
}

// Round 3
// 770.309 us; speedup vs baseline: 2.5346x; 1.5719x over previous
//
#include <hip/hip_runtime.h>
#include <hip/hip_bf16.h>
#include <cstdint>
#include <cstddef>

#define HIDDEN_ 4096
#define NHEAD 32
#define HDIM 128
#define SEQ 2048
#define BATCH 2
#define MROWS (BATCH * SEQ)      // 4096
#define QKVN (3 * HIDDEN_)       // 12288

typedef __bf16 bf16;
typedef __bf16 bf16x8 __attribute__((ext_vector_type(8)));
typedef float f32x4 __attribute__((ext_vector_type(4)));

#define PH_BAR do { asm volatile("" ::: "memory"); __builtin_amdgcn_s_barrier(); asm volatile("" ::: "memory"); } while (0)
#define MFMA_(d, a_, b_) (d) = __builtin_amdgcn_mfma_f32_16x16x32_bf16((a_), (b_), (d), 0, 0, 0)

// ---------------- cast fp32 -> bf16, 8 elems/thread ----------------
__global__ __launch_bounds__(256) void cast_bf16_k(const float* __restrict__ in,
                                                   bf16* __restrict__ out, int n) {
  int i = (blockIdx.x * 256 + threadIdx.x) * 8;
  if (i >= n) return;
  f32x4 a = *(const f32x4*)(in + i);
  f32x4 b = *(const f32x4*)(in + i + 4);
  bf16x8 o;
  o[0] = (bf16)a[0]; o[1] = (bf16)a[1]; o[2] = (bf16)a[2]; o[3] = (bf16)a[3];
  o[4] = (bf16)b[0]; o[5] = (bf16)b[1]; o[6] = (bf16)b[2]; o[7] = (bf16)b[3];
  *(bf16x8*)(out + i) = o;
}

// ---------------- transpose + cast: in[R][C] fp32 -> out[C][R] bf16 ----------------
__global__ __launch_bounds__(256) void transpose_cast_k(const float* __restrict__ in,
                                                        bf16* __restrict__ out,
                                                        int R, int C) {
  __shared__ float tile[32][33];
  int c0 = blockIdx.x * 32, r0 = blockIdx.y * 32;
  int tx = threadIdx.x & 31, ty = threadIdx.x >> 5;  // 32 x 8
#pragma unroll
  for (int i = 0; i < 4; i++) {
    int r = ty + i * 8;
    tile[r][tx] = in[(size_t)(r0 + r) * C + (c0 + tx)];
  }
  __syncthreads();
#pragma unroll
  for (int i = 0; i < 4; i++) {
    int r = ty + i * 8;
    out[(size_t)(c0 + r) * R + (r0 + tx)] = (bf16)tile[tx][r];
  }
}

// ---------------- 256x256 8-phase GEMM: A[M][K] x BT[N][K] -> C[M][N] ----------------
// 512 threads = 8 waves (2 M x 4 N), per-wave C = 128x64. BK=64, 2 K-tiles/iter.
// LDS 128 KiB: A0/A1/B0/B1 tiles of 256x64 bf16, XOR-swizzled (byte ^= (row&7)<<4)
// via pre-swizzled global source (linear global_load_lds dest) + swizzled ds_read.
// Counted vmcnt(2)/vmcnt(6) at phases 3/7 only; raw s_barrier (no vmcnt(0) drain).
// EPI=0: scatter into Q[B,H,S,D], K[B,H,S,D], Vt[B,H,D,S] bf16 with bias.
// EPI=1: fp32 [M][N] with bias.
template <int EPI>
__global__ __launch_bounds__(512, 2) void gemm256_k(
    const bf16* __restrict__ A, const bf16* __restrict__ BT,
    const float* __restrict__ bias, float* __restrict__ outF,
    bf16* __restrict__ Qb, bf16* __restrict__ Kb, bf16* __restrict__ Vt,
    int M, int N, int K, int nbx) {
  __shared__ char lds[131072];
  char* const A0 = lds;             // buf0 A (even K-tiles), 32 KB = [256][64] bf16
  char* const A1 = lds + 32768;     // buf1 A (odd K-tiles)
  char* const B0 = lds + 65536;     // buf0 B
  char* const B1 = lds + 98304;     // buf1 B

  const int tid = threadIdx.x;
  const int w = tid >> 6, l = tid & 63;
  const int lg = l >> 4, cl = l & 15;
  const int wm = (w >> 2) * 128;    // wave M offset within tile
  const int wn = (w & 3) * 64;      // wave N offset within tile

  // bijective XCD swizzle (gridDim.x % 8 == 0)
  const int cpx = (int)gridDim.x >> 3;
  const int bid = blockIdx.x;
  const int swz = (bid & 7) * cpx + (bid >> 3);
  const int bx = swz % nbx, by = swz / nbx;
  const int m0 = by * 256, n0 = bx * 256;

  const int NT = K >> 6;   // 64-wide K tiles
  const int NI = K >> 7;   // iterations (2 tiles each)

  auto stageA = [&](char* buf, int half, int kt) {
#pragma unroll
    for (int i = 0; i < 2; ++i) {
      const int ci = i * 512 + tid;
      const int r = ci >> 3;
      const int cb = ((ci & 7) << 4) ^ ((r & 7) << 4);
      const bf16* s = A + (size_t)(m0 + half * 128 + r) * K + kt * 64 + (cb >> 1);
      __builtin_amdgcn_global_load_lds(
          (const __attribute__((address_space(1))) void*)s,
          (__attribute__((address_space(3))) void*)(buf + half * 16384 + ci * 16), 16, 0, 0);
    }
  };
  auto stageB = [&](char* buf, int half, int kt) {
#pragma unroll
    for (int i = 0; i < 2; ++i) {
      const int ci = i * 512 + tid;
      const int r = ci >> 3;
      const int cb = ((ci & 7) << 4) ^ ((r & 7) << 4);
      const bf16* s = BT + (size_t)(n0 + half * 128 + r) * K + kt * 64 + (cb >> 1);
      __builtin_amdgcn_global_load_lds(
          (const __attribute__((address_space(1))) void*)s,
          (__attribute__((address_space(3))) void*)(buf + half * 16384 + ci * 16), 16, 0, 0);
    }
  };
  auto rdA = [&](const char* buf, int mf, int ks) -> bf16x8 {
    const int r = wm + mf * 16 + cl;
    const int cb = (ks * 64 + lg * 16) ^ ((r & 7) << 4);
    return *(const bf16x8*)(buf + r * 128 + cb);
  };
  auto rdB = [&](const char* buf, int nf, int ks) -> bf16x8 {
    const int r = wn + nf * 16 + cl;
    const int cb = (ks * 64 + lg * 16) ^ ((r & 7) << 4);
    return *(const bf16x8*)(buf + r * 128 + cb);
  };

  f32x4 acc[8][4] = {};
  bf16x8 alo[4][2], ahi[4][2], blo[2][2], bhi[2][2];

  // ---- prologue: tile0 full -> buf0; tile1 {Bh0,Bh1,Ah0} -> buf1 (Ah1 at ph0) ----
  stageA(A0, 0, 0); stageA(A0, 1, 0); stageB(B0, 0, 0); stageB(B0, 1, 0);
  stageB(B1, 0, 1); stageB(B1, 1, 1); stageA(A1, 0, 1);
  asm volatile("s_waitcnt vmcnt(6)" ::: "memory");   // tile0 landed
  PH_BAR;

  for (int j = 0; j < NI; ++j) {
    const int tu = (2 * j + 2) & (NT - 1);   // next even tile -> buf0
    const int tv = (2 * j + 3) & (NT - 1);   // next odd tile  -> buf1

    // -------- phase 0: reads buf0 (alo, blo); stage tile(2j+1).Ah1 -> buf1 --------
#pragma unroll
    for (int mf = 0; mf < 4; ++mf) { alo[mf][0] = rdA(A0, mf, 0); alo[mf][1] = rdA(A0, mf, 1); }
#pragma unroll
    for (int nf = 0; nf < 2; ++nf) { blo[nf][0] = rdB(B0, nf, 0); blo[nf][1] = rdB(B0, nf, 1); }
    stageA(A1, 1, (2 * j + 1) & (NT - 1));
    PH_BAR;
    __builtin_amdgcn_s_setprio(1);
#pragma unroll
    for (int mf = 0; mf < 4; ++mf)
#pragma unroll
      for (int nf = 0; nf < 2; ++nf)
#pragma unroll
        for (int ks = 0; ks < 2; ++ks) MFMA_(acc[mf][nf], alo[mf][ks], blo[nf][ks]);
    __builtin_amdgcn_s_setprio(0);
    PH_BAR;

    // -------- phase 1: reads buf0 (bhi) --------
#pragma unroll
    for (int nf = 0; nf < 2; ++nf) { bhi[nf][0] = rdB(B0, 2 + nf, 0); bhi[nf][1] = rdB(B0, 2 + nf, 1); }
    PH_BAR;
    __builtin_amdgcn_s_setprio(1);
#pragma unroll
    for (int mf = 0; mf < 4; ++mf)
#pragma unroll
      for (int nf = 0; nf < 2; ++nf)
#pragma unroll
        for (int ks = 0; ks < 2; ++ks) MFMA_(acc[mf][2 + nf], alo[mf][ks], bhi[nf][ks]);
    __builtin_amdgcn_s_setprio(0);
    PH_BAR;

    // -------- phase 2: reads buf0 (ahi) --------
#pragma unroll
    for (int mf = 0; mf < 4; ++mf) { ahi[mf][0] = rdA(A0, 4 + mf, 0); ahi[mf][1] = rdA(A0, 4 + mf, 1); }
    PH_BAR;
    __builtin_amdgcn_s_setprio(1);
#pragma unroll
    for (int mf = 0; mf < 4; ++mf)
#pragma unroll
      for (int nf = 0; nf < 2; ++nf)
#pragma unroll
        for (int ks = 0; ks < 2; ++ks) MFMA_(acc[4 + mf][2 + nf], ahi[mf][ks], bhi[nf][ks]);
    __builtin_amdgcn_s_setprio(0);
    PH_BAR;

    // -------- phase 3: stage tu.Ah0 -> buf0; vmcnt(2) guards buf1 tile --------
    stageA(A0, 0, tu);
    PH_BAR;
    __builtin_amdgcn_s_setprio(1);
#pragma unroll
    for (int mf = 0; mf < 4; ++mf)
#pragma unroll
      for (int nf = 0; nf < 2; ++nf)
#pragma unroll
        for (int ks = 0; ks < 2; ++ks) MFMA_(acc[4 + mf][nf], ahi[mf][ks], blo[nf][ks]);
    __builtin_amdgcn_s_setprio(0);
    asm volatile("s_waitcnt vmcnt(2)" ::: "memory");  // tile(2j+1) resident in buf1
    PH_BAR;

    // -------- phase 4: reads buf1 (alo, blo); stage tu.Ah1 -> buf0 --------
#pragma unroll
    for (int mf = 0; mf < 4; ++mf) { alo[mf][0] = rdA(A1, mf, 0); alo[mf][1] = rdA(A1, mf, 1); }
#pragma unroll
    for (int nf = 0; nf < 2; ++nf) { blo[nf][0] = rdB(B1, nf, 0); blo[nf][1] = rdB(B1, nf, 1); }
    stageA(A0, 1, tu);
    PH_BAR;
    __builtin_amdgcn_s_setprio(1);
#pragma unroll
    for (int mf = 0; mf < 4; ++mf)
#pragma unroll
      for (int nf = 0; nf < 2; ++nf)
#pragma unroll
        for (int ks = 0; ks < 2; ++ks) MFMA_(acc[mf][nf], alo[mf][ks], blo[nf][ks]);
    __builtin_amdgcn_s_setprio(0);
    PH_BAR;

    // -------- phase 5: reads buf1 (bhi); stage tu.Bh0 -> buf0 --------
#pragma unroll
    for (int nf = 0; nf < 2; ++nf) { bhi[nf][0] = rdB(B1, 2 + nf, 0); bhi[nf][1] = rdB(B1, 2 + nf, 1); }
    stageB(B0, 0, tu);
    PH_BAR;
    __builtin_amdgcn_s_setprio(1);
#pragma unroll
    for (int mf = 0; mf < 4; ++mf)
#pragma unroll
      for (int nf = 0; nf < 2; ++nf)
#pragma unroll
        for (int ks = 0; ks < 2; ++ks) MFMA_(acc[mf][2 + nf], alo[mf][ks], bhi[nf][ks]);
    __builtin_amdgcn_s_setprio(0);
    PH_BAR;

    // -------- phase 6: reads buf1 (ahi); stage tu.Bh1 -> buf0, tv.Bh0 -> buf1 --------
#pragma unroll
    for (int mf = 0; mf < 4; ++mf) { ahi[mf][0] = rdA(A1, 4 + mf, 0); ahi[mf][1] = rdA(A1, 4 + mf, 1); }
    stageB(B0, 1, tu);
    stageB(B1, 0, tv);
    PH_BAR;
    __builtin_amdgcn_s_setprio(1);
#pragma unroll
    for (int mf = 0; mf < 4; ++mf)
#pragma unroll
      for (int nf = 0; nf < 2; ++nf)
#pragma unroll
        for (int ks = 0; ks < 2; ++ks) MFMA_(acc[4 + mf][2 + nf], ahi[mf][ks], bhi[nf][ks]);
    __builtin_amdgcn_s_setprio(0);
    PH_BAR;

    // -------- phase 7: stage tv.Bh1, tv.Ah0 -> buf1; vmcnt(6) guards buf0 tile --------
    stageB(B1, 1, tv);
    stageA(A1, 0, tv);
    PH_BAR;
    __builtin_amdgcn_s_setprio(1);
#pragma unroll
    for (int mf = 0; mf < 4; ++mf)
#pragma unroll
      for (int nf = 0; nf < 2; ++nf)
#pragma unroll
        for (int ks = 0; ks < 2; ++ks) MFMA_(acc[4 + mf][nf], ahi[mf][ks], blo[nf][ks]);
    __builtin_amdgcn_s_setprio(0);
    asm volatile("s_waitcnt vmcnt(6)" ::: "memory");  // tile tu resident in buf0
    PH_BAR;
  }

  // ---- epilogue: bias + store/scatter ----
#pragma unroll
  for (int mf = 0; mf < 8; ++mf) {
#pragma unroll
    for (int nf = 0; nf < 4; ++nf) {
      const int col = n0 + wn + nf * 16 + cl;
      const float bv = bias[col];
#pragma unroll
      for (int r = 0; r < 4; ++r) {
        const int row = m0 + wm + mf * 16 + lg * 4 + r;
        const float v = acc[mf][nf][r] + bv;
        if (EPI == 0) {
          const int which = col >> 12, rem = col & 4095;
          const int h = rem >> 7, d = rem & 127;
          const int b = row >> 11, s = row & 2047;
          const size_t bh = (size_t)b * NHEAD + h;
          if (which == 0)      Qb[(bh * SEQ + s) * HDIM + d] = (bf16)v;
          else if (which == 1) Kb[(bh * SEQ + s) * HDIM + d] = (bf16)v;
          else                 Vt[(bh * HDIM + d) * SEQ + s] = (bf16)v;
        } else {
          outF[(size_t)row * N + col] = v;
        }
      }
    }
  }
}

// ---------------- flash attention: LDS-staged, double-buffered, swizzled ----------------
__global__ __launch_bounds__(512, 2) void attn_k(const bf16* __restrict__ Qb,
                                                 const bf16* __restrict__ Kb,
                                                 const bf16* __restrict__ Vt,
                                                 bf16* __restrict__ ctx) {
  __shared__ bf16 Ks[2][64 * 128];   // 2 x 16 KB
  __shared__ bf16 Vs[2][128 * 64];   // 2 x 16 KB
  __shared__ bf16 Pl[8][16 * 64];    // 16 KB, per-wave P tile (swizzled)
  const int tid = threadIdx.x, w = tid >> 6, l = tid & 63;
  const int bid = blockIdx.x;
  const int qt = 15 - (bid >> 6);          // longest blocks first
  const int bh = bid & 63;
  const int h = bh & (NHEAD - 1), b = bh >> 5;
  const int qbase = qt * 128 + w * 16;
  const int nt = 2 * qt + 2;               // KV tiles of 64 covering rows < qt*128+128
  const float slope = exp2f(-0.25f * (float)(h + 1));
  const float scale = 1.0f / 128.0f;
  const int lg = l >> 4, cl = l & 15;

  const bf16* Qp = Qb + (size_t)bh * SEQ * HDIM;
  const bf16* Kp = Kb + (size_t)bh * SEQ * HDIM;
  const bf16* Vp = Vt + (size_t)bh * HDIM * SEQ;
  char* plb = (char*)&Pl[w][0];

  bf16x8 qf[4];
#pragma unroll
  for (int kb = 0; kb < 4; kb++)
    qf[kb] = *(const bf16x8*)&Qp[(size_t)(qbase + cl) * HDIM + kb * 32 + lg * 8];

  float mi[4], li[4];
#pragma unroll
  for (int r = 0; r < 4; r++) { mi[r] = -3.0e38f; li[r] = 0.0f; }
  f32x4 oacc[8] = {};

  auto stage = [&](int buf, int t) {
    const int kv0 = t * 64;
#pragma unroll
    for (int i = 0; i < 2; i++) {
      const int ci = i * 512 + tid;
      {  // K: 256B rows
        const int r = ci >> 4;
        const int cbl = ((ci & 15) << 4) ^ ((r & 7) << 4);
        const bf16* src = Kp + (size_t)(kv0 + r) * HDIM + (cbl >> 1);
        __builtin_amdgcn_global_load_lds(
            (const __attribute__((address_space(1))) void*)src,
            (__attribute__((address_space(3))) void*)((char*)&Ks[buf][0] + ci * 16), 16, 0, 0);
      }
      {  // V: 128B rows
        const int r = ci >> 3;
        const int cbl = ((ci & 7) << 4) ^ ((r & 7) << 4);
        const bf16* src = Vp + (size_t)r * SEQ + kv0 + (cbl >> 1);
        __builtin_amdgcn_global_load_lds(
            (const __attribute__((address_space(1))) void*)src,
            (__attribute__((address_space(3))) void*)((char*)&Vs[buf][0] + ci * 16), 16, 0, 0);
      }
    }
  };

  stage(0, 0);
  __syncthreads();

  for (int t = 0; t < nt; ++t) {
    const int cur = t & 1;
    if (t + 1 < nt) stage(cur ^ 1, t + 1);
    const int kv0 = t * 64;

    if (kv0 <= qbase + 15) {
      char* ksb = (char*)&Ks[cur][0];
      char* vsb = (char*)&Vs[cur][0];
      f32x4 sacc[4];
#pragma unroll
      for (int nb = 0; nb < 4; nb++) {
        f32x4 a = {};
#pragma unroll
        for (int kb = 0; kb < 4; kb++) {
          const int row = nb * 16 + cl;
          const int cb = (kb * 64 + lg * 16) ^ ((row & 7) << 4);
          bf16x8 kf = *(const bf16x8*)(ksb + row * 256 + cb);
          a = __builtin_amdgcn_mfma_f32_16x16x32_bf16(qf[kb], kf, a, 0, 0, 0);
        }
        sacc[nb] = a;
      }
      float pm[4], sv[4][4];
#pragma unroll
      for (int r = 0; r < 4; r++) pm[r] = -3.0e38f;
#pragma unroll
      for (int nb = 0; nb < 4; nb++) {
        const int kv = kv0 + nb * 16 + cl;
#pragma unroll
        for (int r = 0; r < 4; r++) {
          const int q = qbase + lg * 4 + r;
          float v = sacc[nb][r] * scale + slope * (float)(kv - q);
          v = (kv <= q) ? v : -3.0e38f;
          sv[nb][r] = v;
          pm[r] = fmaxf(pm[r], v);
        }
      }
#pragma unroll
      for (int r = 0; r < 4; r++) {
        pm[r] = fmaxf(pm[r], __shfl_xor(pm[r], 1));
        pm[r] = fmaxf(pm[r], __shfl_xor(pm[r], 2));
        pm[r] = fmaxf(pm[r], __shfl_xor(pm[r], 4));
        pm[r] = fmaxf(pm[r], __shfl_xor(pm[r], 8));
      }
      float alpha[4], rs[4];
#pragma unroll
      for (int r = 0; r < 4; r++) {
        const float nm = fmaxf(mi[r], pm[r]);
        alpha[r] = __expf(mi[r] - nm);
        mi[r] = nm;
        rs[r] = 0.0f;
      }
#pragma unroll
      for (int nb = 0; nb < 4; nb++) {
#pragma unroll
        for (int r = 0; r < 4; r++) {
          const float p = __expf(sv[nb][r] - mi[r]);
          rs[r] += p;
          const int row = lg * 4 + r;
          *(bf16*)(plb + row * 128 + ((((nb * 16 + cl) << 1)) ^ ((row & 7) << 4))) = (bf16)p;
        }
      }
#pragma unroll
      for (int r = 0; r < 4; r++) {
        rs[r] += __shfl_xor(rs[r], 1);
        rs[r] += __shfl_xor(rs[r], 2);
        rs[r] += __shfl_xor(rs[r], 4);
        rs[r] += __shfl_xor(rs[r], 8);
        li[r] = li[r] * alpha[r] + rs[r];
      }
#pragma unroll
      for (int db = 0; db < 8; db++)
#pragma unroll
        for (int r = 0; r < 4; r++) oacc[db][r] *= alpha[r];
      bf16x8 pa[2];
#pragma unroll
      for (int ks = 0; ks < 2; ks++) {
        const int cb = (ks * 64 + lg * 16) ^ ((cl & 7) << 4);
        pa[ks] = *(const bf16x8*)(plb + cl * 128 + cb);
      }
#pragma unroll
      for (int db = 0; db < 8; db++) {
        f32x4 o = oacc[db];
#pragma unroll
        for (int ks = 0; ks < 2; ks++) {
          const int row = db * 16 + cl;
          const int cb = (ks * 64 + lg * 16) ^ ((row & 7) << 4);
          bf16x8 vf = *(const bf16x8*)(vsb + row * 128 + cb);
          o = __builtin_amdgcn_mfma_f32_16x16x32_bf16(pa[ks], vf, o, 0, 0, 0);
        }
        oacc[db] = o;
      }
    }
    __syncthreads();
  }

  float inv[4];
#pragma unroll
  for (int r = 0; r < 4; r++) inv[r] = 1.0f / li[r];
#pragma unroll
  for (int db = 0; db < 8; db++) {
#pragma unroll
    for (int r = 0; r < 4; r++) {
      const int q = qbase + lg * 4 + r;
      ctx[((size_t)(b * SEQ + q)) * HIDDEN_ + h * HDIM + db * 16 + cl] = (bf16)(oacc[db][r] * inv[r]);
    }
  }
}

// ---------------- launcher ----------------
extern "C" void kernel_launch(void* const* d_in, const int* in_sizes, int n_in,
                              void* d_out, int out_size, void* d_ws, size_t ws_size,
                              hipStream_t stream) {
  const float* hs     = (const float*)d_in[0];
  const float* w_attn = (const float*)d_in[1];
  const float* b_attn = (const float*)d_in[2];
  const float* w_proj = (const float*)d_in[3];
  const float* b_proj = (const float*)d_in[4];
  float* out = (float*)d_out;

  char* ws = (char*)d_ws;
  bf16* Xb  = (bf16*)(ws + 0);           // [4096][4096]        33.5 MB
  bf16* WaT = (bf16*)(ws + 33554432);    // [12288][4096]      100.7 MB
  bf16* WpT = (bf16*)(ws + 134217728);   // [4096][4096]        33.5 MB
  bf16* Qb  = (bf16*)(ws + 167772160);   // [B,H,S,D]           33.5 MB
  bf16* Kb  = (bf16*)(ws + 201326592);   // [B,H,S,D]           33.5 MB
  bf16* Vt  = (bf16*)(ws + 234881024);   // [B,H,D,S]           33.5 MB
  bf16* ctx = (bf16*)(ws + 268435456);   // [4096][4096]        33.5 MB

  cast_bf16_k<<<(MROWS * HIDDEN_) / (256 * 8), 256, 0, stream>>>(hs, Xb, MROWS * HIDDEN_);
  transpose_cast_k<<<dim3(QKVN / 32, HIDDEN_ / 32), 256, 0, stream>>>(w_attn, WaT, HIDDEN_, QKVN);
  transpose_cast_k<<<dim3(HIDDEN_ / 32, HIDDEN_ / 32), 256, 0, stream>>>(w_proj, WpT, HIDDEN_, HIDDEN_);

  gemm256_k<0><<<dim3((QKVN / 256) * (MROWS / 256)), 512, 0, stream>>>(
      Xb, WaT, b_attn, nullptr, Qb, Kb, Vt, MROWS, QKVN, HIDDEN_, QKVN / 256);

  attn_k<<<16 * 64, 512, 0, stream>>>(Qb, Kb, Vt, ctx);

  gemm256_k<1><<<dim3((HIDDEN_ / 256) * (MROWS / 256)), 512, 0, stream>>>(
      ctx, WpT, b_proj, out, nullptr, nullptr, nullptr, MROWS, HIDDEN_, HIDDEN_, HIDDEN_ / 256);
}

// Round 5
// 765.353 us; speedup vs baseline: 2.5511x; 1.0065x over previous
//
#include <hip/hip_runtime.h>
#include <hip/hip_bf16.h>
#include <cstdint>
#include <cstddef>

#define HIDDEN_ 4096
#define NHEAD 32
#define HDIM 128
#define SEQ 2048
#define BATCH 2
#define MROWS (BATCH * SEQ)      // 4096
#define QKVN (3 * HIDDEN_)       // 12288

typedef __bf16 bf16;
typedef __bf16 bf16x8 __attribute__((ext_vector_type(8)));
typedef float f32x4 __attribute__((ext_vector_type(4)));

#define PH_BAR do { asm volatile("" ::: "memory"); __builtin_amdgcn_s_barrier(); asm volatile("" ::: "memory"); } while (0)
#define MFMA_(d, a_, b_) (d) = __builtin_amdgcn_mfma_f32_16x16x32_bf16((a_), (b_), (d), 0, 0, 0)

// ---------------- cast fp32 -> bf16, 8 elems/thread ----------------
__global__ __launch_bounds__(256) void cast_bf16_k(const float* __restrict__ in,
                                                   bf16* __restrict__ out, int n) {
  int i = (blockIdx.x * 256 + threadIdx.x) * 8;
  if (i >= n) return;
  f32x4 a = *(const f32x4*)(in + i);
  f32x4 b = *(const f32x4*)(in + i + 4);
  bf16x8 o;
  o[0] = (bf16)a[0]; o[1] = (bf16)a[1]; o[2] = (bf16)a[2]; o[3] = (bf16)a[3];
  o[4] = (bf16)b[0]; o[5] = (bf16)b[1]; o[6] = (bf16)b[2]; o[7] = (bf16)b[3];
  *(bf16x8*)(out + i) = o;
}

// ---------------- transpose + cast: in[R][C] fp32 -> out[C][R] bf16 ----------------
__global__ __launch_bounds__(256) void transpose_cast_k(const float* __restrict__ in,
                                                        bf16* __restrict__ out,
                                                        int R, int C) {
  __shared__ float tile[32][33];
  int c0 = blockIdx.x * 32, r0 = blockIdx.y * 32;
  int tx = threadIdx.x & 31, ty = threadIdx.x >> 5;  // 32 x 8
#pragma unroll
  for (int i = 0; i < 4; i++) {
    int r = ty + i * 8;
    tile[r][tx] = in[(size_t)(r0 + r) * C + (c0 + tx)];
  }
  __syncthreads();
#pragma unroll
  for (int i = 0; i < 4; i++) {
    int r = ty + i * 8;
    out[(size_t)(c0 + r) * R + (r0 + tx)] = (bf16)tile[tx][r];
  }
}

// ---------------- 256x256 8-phase GEMM: A[M][K] x BT[N][K] -> C[M][N] ----------------
// 512 threads = 8 waves (2 M x 4 N), per-wave C = 128x64. BK=64, 2 K-tiles/iter.
// LDS 128 KiB: A0/A1/B0/B1 tiles of 256x64 bf16, XOR-swizzled (byte ^= (row&7)<<4)
// via pre-swizzled global source (linear global_load_lds dest) + swizzled ds_read.
//
// READ GRANULARITY IS QUARTERS (racy if staged by halves too early!):
//   A rows 0-63/128-191 read at ph0(ph4), rows 64-127/192-255 at ph2(ph6)
//   B rows {0-31,64-95,128-159,192-223} at ph0(ph4), rest at ph1(ph5)
// => earliest legal stage: B0:ph2, A0:ph3, B1:ph6, A1:ph7 (A1h1 wraps to ph0).
// Schedule (one vmcnt(6) per half-iter, 3 half-tiles in flight, 3-5 phase cover):
//   ph0: A1h1(tw) | ph2: B0h0+B0h1(tu) | ph3: A0h0(tu), vmcnt(6)
//   ph4: A0h1(tu) | ph6: B1h0+B1h1(tv) | ph7: A1h0(tv), vmcnt(6)
// EPI=0: scatter into Q[B,H,S,D], K[B,H,S,D], Vt[B,H,D,S] bf16 with bias.
// EPI=1: fp32 [M][N] with bias.
template <int EPI>
__global__ __launch_bounds__(512, 2) void gemm256_k(
    const bf16* __restrict__ A, const bf16* __restrict__ BT,
    const float* __restrict__ bias, float* __restrict__ outF,
    bf16* __restrict__ Qb, bf16* __restrict__ Kb, bf16* __restrict__ Vt,
    int M, int N, int K, int nbx) {
  __shared__ char lds[131072];
  char* const A0 = lds;             // buf0 A (even K-tiles), 32 KB = [256][64] bf16
  char* const A1 = lds + 32768;     // buf1 A (odd K-tiles)
  char* const B0 = lds + 65536;     // buf0 B
  char* const B1 = lds + 98304;     // buf1 B

  const int tid = threadIdx.x;
  const int w = tid >> 6, l = tid & 63;
  const int lg = l >> 4, cl = l & 15;
  const int wm = (w >> 2) * 128;    // wave M offset within tile
  const int wn = (w & 3) * 64;      // wave N offset within tile

  // bijective XCD swizzle (gridDim.x % 8 == 0)
  const int cpx = (int)gridDim.x >> 3;
  const int bid = blockIdx.x;
  const int swz = (bid & 7) * cpx + (bid >> 3);
  const int bx = swz % nbx, by = swz / nbx;
  const int m0 = by * 256, n0 = bx * 256;

  const int NT = K >> 6;   // 64-wide K tiles
  const int NI = K >> 7;   // iterations (2 tiles each)

  auto stageA = [&](char* buf, int half, int kt) {
#pragma unroll
    for (int i = 0; i < 2; ++i) {
      const int ci = i * 512 + tid;
      const int r = ci >> 3;
      const int cb = ((ci & 7) << 4) ^ ((r & 7) << 4);
      const bf16* s = A + (size_t)(m0 + half * 128 + r) * K + kt * 64 + (cb >> 1);
      __builtin_amdgcn_global_load_lds(
          (const __attribute__((address_space(1))) void*)s,
          (__attribute__((address_space(3))) void*)(buf + half * 16384 + ci * 16), 16, 0, 0);
    }
  };
  auto stageB = [&](char* buf, int half, int kt) {
#pragma unroll
    for (int i = 0; i < 2; ++i) {
      const int ci = i * 512 + tid;
      const int r = ci >> 3;
      const int cb = ((ci & 7) << 4) ^ ((r & 7) << 4);
      const bf16* s = BT + (size_t)(n0 + half * 128 + r) * K + kt * 64 + (cb >> 1);
      __builtin_amdgcn_global_load_lds(
          (const __attribute__((address_space(1))) void*)s,
          (__attribute__((address_space(3))) void*)(buf + half * 16384 + ci * 16), 16, 0, 0);
    }
  };
  auto rdA = [&](const char* buf, int mf, int ks) -> bf16x8 {
    const int r = wm + mf * 16 + cl;
    const int cb = (ks * 64 + lg * 16) ^ ((r & 7) << 4);
    return *(const bf16x8*)(buf + r * 128 + cb);
  };
  auto rdB = [&](const char* buf, int nf, int ks) -> bf16x8 {
    const int r = wn + nf * 16 + cl;
    const int cb = (ks * 64 + lg * 16) ^ ((r & 7) << 4);
    return *(const bf16x8*)(buf + r * 128 + cb);
  };

  f32x4 acc[8][4] = {};
  bf16x8 alo[4][2], ahi[4][2], blo[2][2], bhi[2][2];

  // ---- prologue: tile0 (8 ops) -> buf0, then buf1 trio (6 ops); vmcnt(6) drains tile0 ----
  stageA(A0, 0, 0); stageB(B0, 0, 0); stageA(A0, 1, 0); stageB(B0, 1, 0);
  stageB(B1, 0, 1); stageB(B1, 1, 1); stageA(A1, 0, 1);
  asm volatile("s_waitcnt vmcnt(6)" ::: "memory");   // tile0 landed
  PH_BAR;

  for (int j = 0; j < NI; ++j) {
    const int tw = (2 * j + 1) & (NT - 1);   // odd tile landing in buf1
    const int tu = (2 * j + 2) & (NT - 1);   // next even tile -> buf0
    const int tv = (2 * j + 3) & (NT - 1);   // next odd tile  -> buf1

    // -------- phase 0: reads A0.lo + B0.lo; stage tw.A1h1 (A1 rows 128-255: read prev ph4/ph6) --------
#pragma unroll
    for (int mf = 0; mf < 4; ++mf) { alo[mf][0] = rdA(A0, mf, 0); alo[mf][1] = rdA(A0, mf, 1); }
#pragma unroll
    for (int nf = 0; nf < 2; ++nf) { blo[nf][0] = rdB(B0, nf, 0); blo[nf][1] = rdB(B0, nf, 1); }
    stageA(A1, 1, tw);
    PH_BAR;
    __builtin_amdgcn_s_setprio(1);
#pragma unroll
    for (int mf = 0; mf < 4; ++mf)
#pragma unroll
      for (int nf = 0; nf < 2; ++nf)
#pragma unroll
        for (int ks = 0; ks < 2; ++ks) MFMA_(acc[mf][nf], alo[mf][ks], blo[nf][ks]);
    __builtin_amdgcn_s_setprio(0);
    PH_BAR;

    // -------- phase 1: reads B0.hi; no stage --------
#pragma unroll
    for (int nf = 0; nf < 2; ++nf) { bhi[nf][0] = rdB(B0, 2 + nf, 0); bhi[nf][1] = rdB(B0, 2 + nf, 1); }
    PH_BAR;
    __builtin_amdgcn_s_setprio(1);
#pragma unroll
    for (int mf = 0; mf < 4; ++mf)
#pragma unroll
      for (int nf = 0; nf < 2; ++nf)
#pragma unroll
        for (int ks = 0; ks < 2; ++ks) MFMA_(acc[mf][2 + nf], alo[mf][ks], bhi[nf][ks]);
    __builtin_amdgcn_s_setprio(0);
    PH_BAR;

    // -------- phase 2: reads A0.hi; stage tu.B0h0+B0h1 (B0 fully read by ph1) --------
#pragma unroll
    for (int mf = 0; mf < 4; ++mf) { ahi[mf][0] = rdA(A0, 4 + mf, 0); ahi[mf][1] = rdA(A0, 4 + mf, 1); }
    stageB(B0, 0, tu);
    stageB(B0, 1, tu);
    PH_BAR;
    __builtin_amdgcn_s_setprio(1);
#pragma unroll
    for (int mf = 0; mf < 4; ++mf)
#pragma unroll
      for (int nf = 0; nf < 2; ++nf)
#pragma unroll
        for (int ks = 0; ks < 2; ++ks) MFMA_(acc[4 + mf][2 + nf], ahi[mf][ks], bhi[nf][ks]);
    __builtin_amdgcn_s_setprio(0);
    PH_BAR;

    // -------- phase 3: stage tu.A0h0 (A0 fully read by ph2); vmcnt(6) drains tile tw --------
    stageA(A0, 0, tu);
    PH_BAR;
    __builtin_amdgcn_s_setprio(1);
#pragma unroll
    for (int mf = 0; mf < 4; ++mf)
#pragma unroll
      for (int nf = 0; nf < 2; ++nf)
#pragma unroll
        for (int ks = 0; ks < 2; ++ks) MFMA_(acc[4 + mf][nf], ahi[mf][ks], blo[nf][ks]);
    __builtin_amdgcn_s_setprio(0);
    asm volatile("s_waitcnt vmcnt(6)" ::: "memory");  // tile tw resident in buf1
    PH_BAR;

    // -------- phase 4: reads A1.lo + B1.lo; stage tu.A0h1 --------
#pragma unroll
    for (int mf = 0; mf < 4; ++mf) { alo[mf][0] = rdA(A1, mf, 0); alo[mf][1] = rdA(A1, mf, 1); }
#pragma unroll
    for (int nf = 0; nf < 2; ++nf) { blo[nf][0] = rdB(B1, nf, 0); blo[nf][1] = rdB(B1, nf, 1); }
    stageA(A0, 1, tu);
    PH_BAR;
    __builtin_amdgcn_s_setprio(1);
#pragma unroll
    for (int mf = 0; mf < 4; ++mf)
#pragma unroll
      for (int nf = 0; nf < 2; ++nf)
#pragma unroll
        for (int ks = 0; ks < 2; ++ks) MFMA_(acc[mf][nf], alo[mf][ks], blo[nf][ks]);
    __builtin_amdgcn_s_setprio(0);
    PH_BAR;

    // -------- phase 5: reads B1.hi; no stage --------
#pragma unroll
    for (int nf = 0; nf < 2; ++nf) { bhi[nf][0] = rdB(B1, 2 + nf, 0); bhi[nf][1] = rdB(B1, 2 + nf, 1); }
    PH_BAR;
    __builtin_amdgcn_s_setprio(1);
#pragma unroll
    for (int mf = 0; mf < 4; ++mf)
#pragma unroll
      for (int nf = 0; nf < 2; ++nf)
#pragma unroll
        for (int ks = 0; ks < 2; ++ks) MFMA_(acc[mf][2 + nf], alo[mf][ks], bhi[nf][ks]);
    __builtin_amdgcn_s_setprio(0);
    PH_BAR;

    // -------- phase 6: reads A1.hi; stage tv.B1h0+B1h1 (B1 fully read by ph5) --------
#pragma unroll
    for (int mf = 0; mf < 4; ++mf) { ahi[mf][0] = rdA(A1, 4 + mf, 0); ahi[mf][1] = rdA(A1, 4 + mf, 1); }
    stageB(B1, 0, tv);
    stageB(B1, 1, tv);
    PH_BAR;
    __builtin_amdgcn_s_setprio(1);
#pragma unroll
    for (int mf = 0; mf < 4; ++mf)
#pragma unroll
      for (int nf = 0; nf < 2; ++nf)
#pragma unroll
        for (int ks = 0; ks < 2; ++ks) MFMA_(acc[4 + mf][2 + nf], ahi[mf][ks], bhi[nf][ks]);
    __builtin_amdgcn_s_setprio(0);
    PH_BAR;

    // -------- phase 7: stage tv.A1h0 (A1 fully read by ph6); vmcnt(6) drains tile tu --------
    stageA(A1, 0, tv);
    PH_BAR;
    __builtin_amdgcn_s_setprio(1);
#pragma unroll
    for (int mf = 0; mf < 4; ++mf)
#pragma unroll
      for (int nf = 0; nf < 2; ++nf)
#pragma unroll
        for (int ks = 0; ks < 2; ++ks) MFMA_(acc[4 + mf][nf], ahi[mf][ks], blo[nf][ks]);
    __builtin_amdgcn_s_setprio(0);
    asm volatile("s_waitcnt vmcnt(6)" ::: "memory");  // tile tu resident in buf0
    PH_BAR;
  }

  // ---- epilogue: bias + store/scatter ----
#pragma unroll
  for (int mf = 0; mf < 8; ++mf) {
#pragma unroll
    for (int nf = 0; nf < 4; ++nf) {
      const int col = n0 + wn + nf * 16 + cl;
      const float bv = bias[col];
#pragma unroll
      for (int r = 0; r < 4; ++r) {
        const int row = m0 + wm + mf * 16 + lg * 4 + r;
        const float v = acc[mf][nf][r] + bv;
        if (EPI == 0) {
          const int which = col >> 12, rem = col & 4095;
          const int h = rem >> 7, d = rem & 127;
          const int b = row >> 11, s = row & 2047;
          const size_t bh = (size_t)b * NHEAD + h;
          if (which == 0)      Qb[(bh * SEQ + s) * HDIM + d] = (bf16)v;
          else if (which == 1) Kb[(bh * SEQ + s) * HDIM + d] = (bf16)v;
          else                 Vt[(bh * HDIM + d) * SEQ + s] = (bf16)v;
        } else {
          outF[(size_t)row * N + col] = v;
        }
      }
    }
  }
}

// ---------------- flash attention: LDS-staged, double-buffered, swizzled ----------------
__global__ __launch_bounds__(512, 2) void attn_k(const bf16* __restrict__ Qb,
                                                 const bf16* __restrict__ Kb,
                                                 const bf16* __restrict__ Vt,
                                                 bf16* __restrict__ ctx) {
  __shared__ bf16 Ks[2][64 * 128];   // 2 x 16 KB
  __shared__ bf16 Vs[2][128 * 64];   // 2 x 16 KB
  __shared__ bf16 Pl[8][16 * 64];    // 16 KB, per-wave P tile (swizzled)
  const int tid = threadIdx.x, w = tid >> 6, l = tid & 63;
  const int bid = blockIdx.x;
  const int qt = 15 - (bid >> 6);          // longest blocks first
  const int bh = bid & 63;
  const int h = bh & (NHEAD - 1), b = bh >> 5;
  const int qbase = qt * 128 + w * 16;
  const int nt = 2 * qt + 2;               // KV tiles of 64 covering rows < qt*128+128
  const float slope = exp2f(-0.25f * (float)(h + 1));
  const float scale = 1.0f / 128.0f;
  const int lg = l >> 4, cl = l & 15;

  const bf16* Qp = Qb + (size_t)bh * SEQ * HDIM;
  const bf16* Kp = Kb + (size_t)bh * SEQ * HDIM;
  const bf16* Vp = Vt + (size_t)bh * HDIM * SEQ;
  char* plb = (char*)&Pl[w][0];

  bf16x8 qf[4];
#pragma unroll
  for (int kb = 0; kb < 4; kb++)
    qf[kb] = *(const bf16x8*)&Qp[(size_t)(qbase + cl) * HDIM + kb * 32 + lg * 8];

  float mi[4], li[4];
#pragma unroll
  for (int r = 0; r < 4; r++) { mi[r] = -3.0e38f; li[r] = 0.0f; }
  f32x4 oacc[8] = {};

  auto stage = [&](int buf, int t) {
    const int kv0 = t * 64;
#pragma unroll
    for (int i = 0; i < 2; i++) {
      const int ci = i * 512 + tid;
      {  // K: 256B rows
        const int r = ci >> 4;
        const int cbl = ((ci & 15) << 4) ^ ((r & 7) << 4);
        const bf16* src = Kp + (size_t)(kv0 + r) * HDIM + (cbl >> 1);
        __builtin_amdgcn_global_load_lds(
            (const __attribute__((address_space(1))) void*)src,
            (__attribute__((address_space(3))) void*)((char*)&Ks[buf][0] + ci * 16), 16, 0, 0);
      }
      {  // V: 128B rows
        const int r = ci >> 3;
        const int cbl = ((ci & 7) << 4) ^ ((r & 7) << 4);
        const bf16* src = Vp + (size_t)r * SEQ + kv0 + (cbl >> 1);
        __builtin_amdgcn_global_load_lds(
            (const __attribute__((address_space(1))) void*)src,
            (__attribute__((address_space(3))) void*)((char*)&Vs[buf][0] + ci * 16), 16, 0, 0);
      }
    }
  };

  stage(0, 0);
  __syncthreads();

  for (int t = 0; t < nt; ++t) {
    const int cur = t & 1;
    if (t + 1 < nt) stage(cur ^ 1, t + 1);
    const int kv0 = t * 64;

    if (kv0 <= qbase + 15) {
      char* ksb = (char*)&Ks[cur][0];
      char* vsb = (char*)&Vs[cur][0];
      f32x4 sacc[4];
#pragma unroll
      for (int nb = 0; nb < 4; nb++) {
        f32x4 a = {};
#pragma unroll
        for (int kb = 0; kb < 4; kb++) {
          const int row = nb * 16 + cl;
          const int cb = (kb * 64 + lg * 16) ^ ((row & 7) << 4);
          bf16x8 kf = *(const bf16x8*)(ksb + row * 256 + cb);
          a = __builtin_amdgcn_mfma_f32_16x16x32_bf16(qf[kb], kf, a, 0, 0, 0);
        }
        sacc[nb] = a;
      }
      float pm[4], sv[4][4];
#pragma unroll
      for (int r = 0; r < 4; r++) pm[r] = -3.0e38f;
#pragma unroll
      for (int nb = 0; nb < 4; nb++) {
        const int kv = kv0 + nb * 16 + cl;
#pragma unroll
        for (int r = 0; r < 4; r++) {
          const int q = qbase + lg * 4 + r;
          float v = sacc[nb][r] * scale + slope * (float)(kv - q);
          v = (kv <= q) ? v : -3.0e38f;
          sv[nb][r] = v;
          pm[r] = fmaxf(pm[r], v);
        }
      }
#pragma unroll
      for (int r = 0; r < 4; r++) {
        pm[r] = fmaxf(pm[r], __shfl_xor(pm[r], 1));
        pm[r] = fmaxf(pm[r], __shfl_xor(pm[r], 2));
        pm[r] = fmaxf(pm[r], __shfl_xor(pm[r], 4));
        pm[r] = fmaxf(pm[r], __shfl_xor(pm[r], 8));
      }
      float alpha[4], rs[4];
#pragma unroll
      for (int r = 0; r < 4; r++) {
        const float nm = fmaxf(mi[r], pm[r]);
        alpha[r] = __expf(mi[r] - nm);
        mi[r] = nm;
        rs[r] = 0.0f;
      }
#pragma unroll
      for (int nb = 0; nb < 4; nb++) {
#pragma unroll
        for (int r = 0; r < 4; r++) {
          const float p = __expf(sv[nb][r] - mi[r]);
          rs[r] += p;
          const int row = lg * 4 + r;
          *(bf16*)(plb + row * 128 + ((((nb * 16 + cl) << 1)) ^ ((row & 7) << 4))) = (bf16)p;
        }
      }
#pragma unroll
      for (int r = 0; r < 4; r++) {
        rs[r] += __shfl_xor(rs[r], 1);
        rs[r] += __shfl_xor(rs[r], 2);
        rs[r] += __shfl_xor(rs[r], 4);
        rs[r] += __shfl_xor(rs[r], 8);
        li[r] = li[r] * alpha[r] + rs[r];
      }
#pragma unroll
      for (int db = 0; db < 8; db++)
#pragma unroll
        for (int r = 0; r < 4; r++) oacc[db][r] *= alpha[r];
      bf16x8 pa[2];
#pragma unroll
      for (int ks = 0; ks < 2; ks++) {
        const int cb = (ks * 64 + lg * 16) ^ ((cl & 7) << 4);
        pa[ks] = *(const bf16x8*)(plb + cl * 128 + cb);
      }
#pragma unroll
      for (int db = 0; db < 8; db++) {
        f32x4 o = oacc[db];
#pragma unroll
        for (int ks = 0; ks < 2; ks++) {
          const int row = db * 16 + cl;
          const int cb = (ks * 64 + lg * 16) ^ ((row & 7) << 4);
          bf16x8 vf = *(const bf16x8*)(vsb + row * 128 + cb);
          o = __builtin_amdgcn_mfma_f32_16x16x32_bf16(pa[ks], vf, o, 0, 0, 0);
        }
        oacc[db] = o;
      }
    }
    __syncthreads();
  }

  float inv[4];
#pragma unroll
  for (int r = 0; r < 4; r++) inv[r] = 1.0f / li[r];
#pragma unroll
  for (int db = 0; db < 8; db++) {
#pragma unroll
    for (int r = 0; r < 4; r++) {
      const int q = qbase + lg * 4 + r;
      ctx[((size_t)(b * SEQ + q)) * HIDDEN_ + h * HDIM + db * 16 + cl] = (bf16)(oacc[db][r] * inv[r]);
    }
  }
}

// ---------------- launcher ----------------
extern "C" void kernel_launch(void* const* d_in, const int* in_sizes, int n_in,
                              void* d_out, int out_size, void* d_ws, size_t ws_size,
                              hipStream_t stream) {
  const float* hs     = (const float*)d_in[0];
  const float* w_attn = (const float*)d_in[1];
  const float* b_attn = (const float*)d_in[2];
  const float* w_proj = (const float*)d_in[3];
  const float* b_proj = (const float*)d_in[4];
  float* out = (float*)d_out;

  char* ws = (char*)d_ws;
  bf16* Xb  = (bf16*)(ws + 0);           // [4096][4096]        33.5 MB
  bf16* WaT = (bf16*)(ws + 33554432);    // [12288][4096]      100.7 MB
  bf16* WpT = (bf16*)(ws + 134217728);   // [4096][4096]        33.5 MB
  bf16* Qb  = (bf16*)(ws + 167772160);   // [B,H,S,D]           33.5 MB
  bf16* Kb  = (bf16*)(ws + 201326592);   // [B,H,S,D]           33.5 MB
  bf16* Vt  = (bf16*)(ws + 234881024);   // [B,H,D,S]           33.5 MB
  bf16* ctx = (bf16*)(ws + 268435456);   // [4096][4096]        33.5 MB

  cast_bf16_k<<<(MROWS * HIDDEN_) / (256 * 8), 256, 0, stream>>>(hs, Xb, MROWS * HIDDEN_);
  transpose_cast_k<<<dim3(QKVN / 32, HIDDEN_ / 32), 256, 0, stream>>>(w_attn, WaT, HIDDEN_, QKVN);
  transpose_cast_k<<<dim3(HIDDEN_ / 32, HIDDEN_ / 32), 256, 0, stream>>>(w_proj, WpT, HIDDEN_, HIDDEN_);

  gemm256_k<0><<<dim3((QKVN / 256) * (MROWS / 256)), 512, 0, stream>>>(
      Xb, WaT, b_attn, nullptr, Qb, Kb, Vt, MROWS, QKVN, HIDDEN_, QKVN / 256);

  attn_k<<<16 * 64, 512, 0, stream>>>(Qb, Kb, Vt, ctx);

  gemm256_k<1><<<dim3((HIDDEN_ / 256) * (MROWS / 256)), 512, 0, stream>>>(
      ctx, WpT, b_proj, out, nullptr, nullptr, nullptr, MROWS, HIDDEN_, HIDDEN_, HIDDEN_ / 256);
}

// Round 6
// 760.897 us; speedup vs baseline: 2.5660x; 1.0059x over previous
//
#include <hip/hip_runtime.h>
#include <hip/hip_bf16.h>
#include <cstdint>
#include <cstddef>

#define HIDDEN_ 4096
#define NHEAD 32
#define HDIM 128
#define SEQ 2048
#define BATCH 2
#define MROWS (BATCH * SEQ)      // 4096
#define QKVN (3 * HIDDEN_)       // 12288

typedef __bf16 bf16;
typedef __bf16 bf16x8 __attribute__((ext_vector_type(8)));
typedef float f32x4 __attribute__((ext_vector_type(4)));

#define AS1 __attribute__((address_space(1)))
#define AS3 __attribute__((address_space(3)))
#define PH_BAR do { asm volatile("" ::: "memory"); __builtin_amdgcn_s_barrier(); asm volatile("" ::: "memory"); } while (0)
#define MFMA_(d, a_, b_) (d) = __builtin_amdgcn_mfma_f32_16x16x32_bf16((a_), (b_), (d), 0, 0, 0)

// ---------------- cast fp32 -> bf16, 8 elems/thread ----------------
__global__ __launch_bounds__(256) void cast_bf16_k(const float* __restrict__ in,
                                                   bf16* __restrict__ out, int n) {
  int i = (blockIdx.x * 256 + threadIdx.x) * 8;
  if (i >= n) return;
  f32x4 a = *(const f32x4*)(in + i);
  f32x4 b = *(const f32x4*)(in + i + 4);
  bf16x8 o;
  o[0] = (bf16)a[0]; o[1] = (bf16)a[1]; o[2] = (bf16)a[2]; o[3] = (bf16)a[3];
  o[4] = (bf16)b[0]; o[5] = (bf16)b[1]; o[6] = (bf16)b[2]; o[7] = (bf16)b[3];
  *(bf16x8*)(out + i) = o;
}

// ---------------- transpose + cast: in[R][C] fp32 -> out[C][R] bf16 ----------------
__global__ __launch_bounds__(256) void transpose_cast_k(const float* __restrict__ in,
                                                        bf16* __restrict__ out,
                                                        int R, int C) {
  __shared__ float tile[32][33];
  int c0 = blockIdx.x * 32, r0 = blockIdx.y * 32;
  int tx = threadIdx.x & 31, ty = threadIdx.x >> 5;  // 32 x 8
#pragma unroll
  for (int i = 0; i < 4; i++) {
    int r = ty + i * 8;
    tile[r][tx] = in[(size_t)(r0 + r) * C + (c0 + tx)];
  }
  __syncthreads();
#pragma unroll
  for (int i = 0; i < 4; i++) {
    int r = ty + i * 8;
    out[(size_t)(c0 + r) * R + (r0 + tx)] = (bf16)tile[tx][r];
  }
}

// ---------------- 256x256 8-phase GEMM: A[M][K] x BT[N][K] -> C[M][N] ----------------
// 512 threads = 8 waves (2 M x 4 N), per-wave C = 128x64. BK=64, 2 K-tiles/iter.
// LDS 128 KiB: A0/A1/B0/B1 tiles of 256x64 bf16, XOR-swizzled (byte ^= (row&7)<<4)
// via pre-swizzled global source (linear global_load_lds dest) + swizzled ds_read.
//
// SINGLE barrier per phase: {ds_reads || stage-issue || MFMA} share one window.
// Safe because every phase's ds_reads are consumed by that phase's MFMA (lgkmcnt
// drains before the end barrier -> no pending reads cross barriers), and stage(p)
// regions are disjoint from reads(p) (quarter-granular audit):
//   A rows 0-63/128-191 read at ph0(ph4), rows 64-127/192-255 at ph2(ph6)
//   B quarters {0-31,64-95,...} at ph0(ph4), rest at ph1(ph5)
// Stage slots: ph0: A1h1(tw) | ph2: B0h0+B0h1(tu) | ph3: A0h0(tu), vmcnt(6)
//              ph4: A0h1(tu) | ph6: B1h0+B1h1(tv) | ph7: A1h0(tv), vmcnt(6)
// All LDS read offsets and global stage pointers hoisted out of the loop.
// EPI=0: scatter into Q[B,H,S,D], K[B,H,S,D], Vt[B,H,D,S] bf16 with bias.
// EPI=1: fp32 [M][N] with bias.
template <int EPI>
__global__ __launch_bounds__(512, 2) void gemm256_k(
    const bf16* __restrict__ A, const bf16* __restrict__ BT,
    const float* __restrict__ bias, float* __restrict__ outF,
    bf16* __restrict__ Qb, bf16* __restrict__ Kb, bf16* __restrict__ Vt,
    int M, int N, int K, int nbx) {
  __shared__ char lds[131072];
  char* const A0 = lds;             // buf0 A (even K-tiles), 32 KB = [256][64] bf16
  char* const A1 = lds + 32768;     // buf1 A (odd K-tiles)
  char* const B0 = lds + 65536;     // buf0 B
  char* const B1 = lds + 98304;     // buf1 B

  const int tid = threadIdx.x;
  const int w = tid >> 6, l = tid & 63;
  const int lg = l >> 4, cl = l & 15;
  const int wm = (w >> 2) * 128;    // wave M offset within tile
  const int wn = (w & 3) * 64;      // wave N offset within tile

  // bijective XCD swizzle (gridDim.x % 8 == 0)
  const int cpx = (int)gridDim.x >> 3;
  const int bid = blockIdx.x;
  const int swz = (bid & 7) * cpx + (bid >> 3);
  const int bx = swz % nbx, by = swz / nbx;
  const int m0 = by * 256, n0 = bx * 256;

  const int NT = K >> 6;   // 64-wide K tiles
  const int NI = K >> 7;   // iterations (2 tiles each)

  // ---- hoisted global stage pointers (per half, per chunk) ----
  const bf16* gA[2][2]; const bf16* gB[2][2];
#pragma unroll
  for (int half = 0; half < 2; ++half)
#pragma unroll
    for (int i = 0; i < 2; ++i) {
      const int ci = i * 512 + tid;
      const int r = ci >> 3;
      const int cb = ((ci & 7) << 4) ^ ((r & 7) << 4);
      gA[half][i] = A + (size_t)(m0 + half * 128 + r) * K + (cb >> 1);
      gB[half][i] = BT + (size_t)(n0 + half * 128 + r) * K + (cb >> 1);
    }

  // ---- hoisted LDS read byte-offsets ----
  int offA[8][2], offB[4][2];
#pragma unroll
  for (int mf = 0; mf < 8; ++mf) {
    const int r = wm + mf * 16 + cl;
#pragma unroll
    for (int ks = 0; ks < 2; ++ks)
      offA[mf][ks] = r * 128 + ((ks * 64 + lg * 16) ^ ((r & 7) << 4));
  }
#pragma unroll
  for (int nf = 0; nf < 4; ++nf) {
    const int r = wn + nf * 16 + cl;
#pragma unroll
    for (int ks = 0; ks < 2; ++ks)
      offB[nf][ks] = r * 128 + ((ks * 64 + lg * 16) ^ ((r & 7) << 4));
  }

  auto stageA = [&](char* buf, int half, int kt) {
#pragma unroll
    for (int i = 0; i < 2; ++i) {
      const int ci = i * 512 + tid;
      __builtin_amdgcn_global_load_lds((const AS1 void*)(gA[half][i] + kt * 64),
                                       (AS3 void*)(buf + half * 16384 + ci * 16), 16, 0, 0);
    }
  };
  auto stageB = [&](char* buf, int half, int kt) {
#pragma unroll
    for (int i = 0; i < 2; ++i) {
      const int ci = i * 512 + tid;
      __builtin_amdgcn_global_load_lds((const AS1 void*)(gB[half][i] + kt * 64),
                                       (AS3 void*)(buf + half * 16384 + ci * 16), 16, 0, 0);
    }
  };
  auto rdA = [&](const char* buf, int mf, int ks) -> bf16x8 {
    return *(const bf16x8*)(buf + offA[mf][ks]);
  };
  auto rdB = [&](const char* buf, int nf, int ks) -> bf16x8 {
    return *(const bf16x8*)(buf + offB[nf][ks]);
  };

  f32x4 acc[8][4] = {};
  bf16x8 alo[4][2], ahi[4][2], blo[2][2], bhi[2][2];

  // ---- prologue: tile0 (8 ops) -> buf0, then buf1 trio (6 ops); vmcnt(6) drains tile0 ----
  stageA(A0, 0, 0); stageB(B0, 0, 0); stageA(A0, 1, 0); stageB(B0, 1, 0);
  stageB(B1, 0, 1); stageB(B1, 1, 1); stageA(A1, 0, 1);
  asm volatile("s_waitcnt vmcnt(6)" ::: "memory");   // tile0 landed
  PH_BAR;

  for (int j = 0; j < NI; ++j) {
    const int tw = (2 * j + 1) & (NT - 1);   // odd tile landing in buf1
    const int tu = (2 * j + 2) & (NT - 1);   // next even tile -> buf0
    const int tv = (2 * j + 3) & (NT - 1);   // next odd tile  -> buf1

    // -------- phase 0: reads A0.lo + B0.lo; stage tw.A1h1; MFMA q00 --------
#pragma unroll
    for (int mf = 0; mf < 4; ++mf) { alo[mf][0] = rdA(A0, mf, 0); alo[mf][1] = rdA(A0, mf, 1); }
#pragma unroll
    for (int nf = 0; nf < 2; ++nf) { blo[nf][0] = rdB(B0, nf, 0); blo[nf][1] = rdB(B0, nf, 1); }
    stageA(A1, 1, tw);
    __builtin_amdgcn_s_setprio(1);
#pragma unroll
    for (int mf = 0; mf < 4; ++mf)
#pragma unroll
      for (int nf = 0; nf < 2; ++nf)
#pragma unroll
        for (int ks = 0; ks < 2; ++ks) MFMA_(acc[mf][nf], alo[mf][ks], blo[nf][ks]);
    __builtin_amdgcn_s_setprio(0);
    PH_BAR;

    // -------- phase 1: reads B0.hi; MFMA q01 --------
#pragma unroll
    for (int nf = 0; nf < 2; ++nf) { bhi[nf][0] = rdB(B0, 2 + nf, 0); bhi[nf][1] = rdB(B0, 2 + nf, 1); }
    __builtin_amdgcn_s_setprio(1);
#pragma unroll
    for (int mf = 0; mf < 4; ++mf)
#pragma unroll
      for (int nf = 0; nf < 2; ++nf)
#pragma unroll
        for (int ks = 0; ks < 2; ++ks) MFMA_(acc[mf][2 + nf], alo[mf][ks], bhi[nf][ks]);
    __builtin_amdgcn_s_setprio(0);
    PH_BAR;

    // -------- phase 2: reads A0.hi; stage tu.B0h0+B0h1; MFMA q11 --------
#pragma unroll
    for (int mf = 0; mf < 4; ++mf) { ahi[mf][0] = rdA(A0, 4 + mf, 0); ahi[mf][1] = rdA(A0, 4 + mf, 1); }
    stageB(B0, 0, tu);
    stageB(B0, 1, tu);
    __builtin_amdgcn_s_setprio(1);
#pragma unroll
    for (int mf = 0; mf < 4; ++mf)
#pragma unroll
      for (int nf = 0; nf < 2; ++nf)
#pragma unroll
        for (int ks = 0; ks < 2; ++ks) MFMA_(acc[4 + mf][2 + nf], ahi[mf][ks], bhi[nf][ks]);
    __builtin_amdgcn_s_setprio(0);
    PH_BAR;

    // -------- phase 3: stage tu.A0h0; MFMA q10; vmcnt(6) drains tile tw --------
    stageA(A0, 0, tu);
    __builtin_amdgcn_s_setprio(1);
#pragma unroll
    for (int mf = 0; mf < 4; ++mf)
#pragma unroll
      for (int nf = 0; nf < 2; ++nf)
#pragma unroll
        for (int ks = 0; ks < 2; ++ks) MFMA_(acc[4 + mf][nf], ahi[mf][ks], blo[nf][ks]);
    __builtin_amdgcn_s_setprio(0);
    asm volatile("s_waitcnt vmcnt(6)" ::: "memory");  // tile tw resident in buf1
    PH_BAR;

    // -------- phase 4: reads A1.lo + B1.lo; stage tu.A0h1; MFMA q00 --------
#pragma unroll
    for (int mf = 0; mf < 4; ++mf) { alo[mf][0] = rdA(A1, mf, 0); alo[mf][1] = rdA(A1, mf, 1); }
#pragma unroll
    for (int nf = 0; nf < 2; ++nf) { blo[nf][0] = rdB(B1, nf, 0); blo[nf][1] = rdB(B1, nf, 1); }
    stageA(A0, 1, tu);
    __builtin_amdgcn_s_setprio(1);
#pragma unroll
    for (int mf = 0; mf < 4; ++mf)
#pragma unroll
      for (int nf = 0; nf < 2; ++nf)
#pragma unroll
        for (int ks = 0; ks < 2; ++ks) MFMA_(acc[mf][nf], alo[mf][ks], blo[nf][ks]);
    __builtin_amdgcn_s_setprio(0);
    PH_BAR;

    // -------- phase 5: reads B1.hi; MFMA q01 --------
#pragma unroll
    for (int nf = 0; nf < 2; ++nf) { bhi[nf][0] = rdB(B1, 2 + nf, 0); bhi[nf][1] = rdB(B1, 2 + nf, 1); }
    __builtin_amdgcn_s_setprio(1);
#pragma unroll
    for (int mf = 0; mf < 4; ++mf)
#pragma unroll
      for (int nf = 0; nf < 2; ++nf)
#pragma unroll
        for (int ks = 0; ks < 2; ++ks) MFMA_(acc[mf][2 + nf], alo[mf][ks], bhi[nf][ks]);
    __builtin_amdgcn_s_setprio(0);
    PH_BAR;

    // -------- phase 6: reads A1.hi; stage tv.B1h0+B1h1; MFMA q11 --------
#pragma unroll
    for (int mf = 0; mf < 4; ++mf) { ahi[mf][0] = rdA(A1, 4 + mf, 0); ahi[mf][1] = rdA(A1, 4 + mf, 1); }
    stageB(B1, 0, tv);
    stageB(B1, 1, tv);
    __builtin_amdgcn_s_setprio(1);
#pragma unroll
    for (int mf = 0; mf < 4; ++mf)
#pragma unroll
      for (int nf = 0; nf < 2; ++nf)
#pragma unroll
        for (int ks = 0; ks < 2; ++ks) MFMA_(acc[4 + mf][2 + nf], ahi[mf][ks], bhi[nf][ks]);
    __builtin_amdgcn_s_setprio(0);
    PH_BAR;

    // -------- phase 7: stage tv.A1h0; MFMA q10; vmcnt(6) drains tile tu --------
    stageA(A1, 0, tv);
    __builtin_amdgcn_s_setprio(1);
#pragma unroll
    for (int mf = 0; mf < 4; ++mf)
#pragma unroll
      for (int nf = 0; nf < 2; ++nf)
#pragma unroll
        for (int ks = 0; ks < 2; ++ks) MFMA_(acc[4 + mf][nf], ahi[mf][ks], blo[nf][ks]);
    __builtin_amdgcn_s_setprio(0);
    asm volatile("s_waitcnt vmcnt(6)" ::: "memory");  // tile tu resident in buf0
    PH_BAR;
  }

  // ---- epilogue: bias + store/scatter ----
#pragma unroll
  for (int mf = 0; mf < 8; ++mf) {
#pragma unroll
    for (int nf = 0; nf < 4; ++nf) {
      const int col = n0 + wn + nf * 16 + cl;
      const float bv = bias[col];
#pragma unroll
      for (int r = 0; r < 4; ++r) {
        const int row = m0 + wm + mf * 16 + lg * 4 + r;
        const float v = acc[mf][nf][r] + bv;
        if (EPI == 0) {
          const int which = col >> 12, rem = col & 4095;
          const int h = rem >> 7, d = rem & 127;
          const int b = row >> 11, s = row & 2047;
          const size_t bh = (size_t)b * NHEAD + h;
          if (which == 0)      Qb[(bh * SEQ + s) * HDIM + d] = (bf16)v;
          else if (which == 1) Kb[(bh * SEQ + s) * HDIM + d] = (bf16)v;
          else                 Vt[(bh * HDIM + d) * SEQ + s] = (bf16)v;
        } else {
          outF[(size_t)row * N + col] = v;
        }
      }
    }
  }
}

// ---------------- flash attention: LDS-staged, double-buffered, swizzled ----------------
__global__ __launch_bounds__(512, 2) void attn_k(const bf16* __restrict__ Qb,
                                                 const bf16* __restrict__ Kb,
                                                 const bf16* __restrict__ Vt,
                                                 bf16* __restrict__ ctx) {
  __shared__ bf16 Ks[2][64 * 128];   // 2 x 16 KB
  __shared__ bf16 Vs[2][128 * 64];   // 2 x 16 KB
  __shared__ bf16 Pl[8][16 * 64];    // 16 KB, per-wave P tile (swizzled)
  const int tid = threadIdx.x, w = tid >> 6, l = tid & 63;
  const int bid = blockIdx.x;
  const int qt = 15 - (bid >> 6);          // longest blocks first
  const int bh = bid & 63;
  const int h = bh & (NHEAD - 1), b = bh >> 5;
  const int qbase = qt * 128 + w * 16;
  const int nt = 2 * qt + 2;               // KV tiles of 64 covering rows < qt*128+128
  const float slope = exp2f(-0.25f * (float)(h + 1));
  const float scale = 1.0f / 128.0f;
  const int lg = l >> 4, cl = l & 15;

  const bf16* Qp = Qb + (size_t)bh * SEQ * HDIM;
  const bf16* Kp = Kb + (size_t)bh * SEQ * HDIM;
  const bf16* Vp = Vt + (size_t)bh * HDIM * SEQ;
  char* plb = (char*)&Pl[w][0];

  bf16x8 qf[4];
#pragma unroll
  for (int kb = 0; kb < 4; kb++)
    qf[kb] = *(const bf16x8*)&Qp[(size_t)(qbase + cl) * HDIM + kb * 32 + lg * 8];

  float mi[4], li[4];
#pragma unroll
  for (int r = 0; r < 4; r++) { mi[r] = -3.0e38f; li[r] = 0.0f; }
  f32x4 oacc[8] = {};

  auto stage = [&](int buf, int t) {
    const int kv0 = t * 64;
#pragma unroll
    for (int i = 0; i < 2; i++) {
      const int ci = i * 512 + tid;
      {  // K: 256B rows
        const int r = ci >> 4;
        const int cbl = ((ci & 15) << 4) ^ ((r & 7) << 4);
        const bf16* src = Kp + (size_t)(kv0 + r) * HDIM + (cbl >> 1);
        __builtin_amdgcn_global_load_lds(
            (const AS1 void*)src,
            (AS3 void*)((char*)&Ks[buf][0] + ci * 16), 16, 0, 0);
      }
      {  // V: 128B rows
        const int r = ci >> 3;
        const int cbl = ((ci & 7) << 4) ^ ((r & 7) << 4);
        const bf16* src = Vp + (size_t)r * SEQ + kv0 + (cbl >> 1);
        __builtin_amdgcn_global_load_lds(
            (const AS1 void*)src,
            (AS3 void*)((char*)&Vs[buf][0] + ci * 16), 16, 0, 0);
      }
    }
  };

  stage(0, 0);
  __syncthreads();

  for (int t = 0; t < nt; ++t) {
    const int cur = t & 1;
    if (t + 1 < nt) stage(cur ^ 1, t + 1);
    const int kv0 = t * 64;

    if (kv0 <= qbase + 15) {
      char* ksb = (char*)&Ks[cur][0];
      char* vsb = (char*)&Vs[cur][0];
      f32x4 sacc[4];
#pragma unroll
      for (int nb = 0; nb < 4; nb++) {
        f32x4 a = {};
#pragma unroll
        for (int kb = 0; kb < 4; kb++) {
          const int row = nb * 16 + cl;
          const int cb = (kb * 64 + lg * 16) ^ ((row & 7) << 4);
          bf16x8 kf = *(const bf16x8*)(ksb + row * 256 + cb);
          a = __builtin_amdgcn_mfma_f32_16x16x32_bf16(qf[kb], kf, a, 0, 0, 0);
        }
        sacc[nb] = a;
      }
      float pm[4], sv[4][4];
#pragma unroll
      for (int r = 0; r < 4; r++) pm[r] = -3.0e38f;
#pragma unroll
      for (int nb = 0; nb < 4; nb++) {
        const int kv = kv0 + nb * 16 + cl;
#pragma unroll
        for (int r = 0; r < 4; r++) {
          const int q = qbase + lg * 4 + r;
          float v = sacc[nb][r] * scale + slope * (float)(kv - q);
          v = (kv <= q) ? v : -3.0e38f;
          sv[nb][r] = v;
          pm[r] = fmaxf(pm[r], v);
        }
      }
#pragma unroll
      for (int r = 0; r < 4; r++) {
        pm[r] = fmaxf(pm[r], __shfl_xor(pm[r], 1));
        pm[r] = fmaxf(pm[r], __shfl_xor(pm[r], 2));
        pm[r] = fmaxf(pm[r], __shfl_xor(pm[r], 4));
        pm[r] = fmaxf(pm[r], __shfl_xor(pm[r], 8));
      }
      float alpha[4], rs[4];
#pragma unroll
      for (int r = 0; r < 4; r++) {
        const float nm = fmaxf(mi[r], pm[r]);
        alpha[r] = __expf(mi[r] - nm);
        mi[r] = nm;
        rs[r] = 0.0f;
      }
#pragma unroll
      for (int nb = 0; nb < 4; nb++) {
#pragma unroll
        for (int r = 0; r < 4; r++) {
          const float p = __expf(sv[nb][r] - mi[r]);
          rs[r] += p;
          const int row = lg * 4 + r;
          *(bf16*)(plb + row * 128 + ((((nb * 16 + cl) << 1)) ^ ((row & 7) << 4))) = (bf16)p;
        }
      }
#pragma unroll
      for (int r = 0; r < 4; r++) {
        rs[r] += __shfl_xor(rs[r], 1);
        rs[r] += __shfl_xor(rs[r], 2);
        rs[r] += __shfl_xor(rs[r], 4);
        rs[r] += __shfl_xor(rs[r], 8);
        li[r] = li[r] * alpha[r] + rs[r];
      }
#pragma unroll
      for (int db = 0; db < 8; db++)
#pragma unroll
        for (int r = 0; r < 4; r++) oacc[db][r] *= alpha[r];
      bf16x8 pa[2];
#pragma unroll
      for (int ks = 0; ks < 2; ks++) {
        const int cb = (ks * 64 + lg * 16) ^ ((cl & 7) << 4);
        pa[ks] = *(const bf16x8*)(plb + cl * 128 + cb);
      }
#pragma unroll
      for (int db = 0; db < 8; db++) {
        f32x4 o = oacc[db];
#pragma unroll
        for (int ks = 0; ks < 2; ks++) {
          const int row = db * 16 + cl;
          const int cb = (ks * 64 + lg * 16) ^ ((row & 7) << 4);
          bf16x8 vf = *(const bf16x8*)(vsb + row * 128 + cb);
          o = __builtin_amdgcn_mfma_f32_16x16x32_bf16(pa[ks], vf, o, 0, 0, 0);
        }
        oacc[db] = o;
      }
    }
    __syncthreads();
  }

  float inv[4];
#pragma unroll
  for (int r = 0; r < 4; r++) inv[r] = 1.0f / li[r];
#pragma unroll
  for (int db = 0; db < 8; db++) {
#pragma unroll
    for (int r = 0; r < 4; r++) {
      const int q = qbase + lg * 4 + r;
      ctx[((size_t)(b * SEQ + q)) * HIDDEN_ + h * HDIM + db * 16 + cl] = (bf16)(oacc[db][r] * inv[r]);
    }
  }
}

// ---------------- launcher ----------------
extern "C" void kernel_launch(void* const* d_in, const int* in_sizes, int n_in,
                              void* d_out, int out_size, void* d_ws, size_t ws_size,
                              hipStream_t stream) {
  const float* hs     = (const float*)d_in[0];
  const float* w_attn = (const float*)d_in[1];
  const float* b_attn = (const float*)d_in[2];
  const float* w_proj = (const float*)d_in[3];
  const float* b_proj = (const float*)d_in[4];
  float* out = (float*)d_out;

  char* ws = (char*)d_ws;
  bf16* Xb  = (bf16*)(ws + 0);           // [4096][4096]        33.5 MB
  bf16* WaT = (bf16*)(ws + 33554432);    // [12288][4096]      100.7 MB
  bf16* WpT = (bf16*)(ws + 134217728);   // [4096][4096]        33.5 MB
  bf16* Qb  = (bf16*)(ws + 167772160);   // [B,H,S,D]           33.5 MB
  bf16* Kb  = (bf16*)(ws + 201326592);   // [B,H,S,D]           33.5 MB
  bf16* Vt  = (bf16*)(ws + 234881024);   // [B,H,D,S]           33.5 MB
  bf16* ctx = (bf16*)(ws + 268435456);   // [4096][4096]        33.5 MB

  cast_bf16_k<<<(MROWS * HIDDEN_) / (256 * 8), 256, 0, stream>>>(hs, Xb, MROWS * HIDDEN_);
  transpose_cast_k<<<dim3(QKVN / 32, HIDDEN_ / 32), 256, 0, stream>>>(w_attn, WaT, HIDDEN_, QKVN);
  transpose_cast_k<<<dim3(HIDDEN_ / 32, HIDDEN_ / 32), 256, 0, stream>>>(w_proj, WpT, HIDDEN_, HIDDEN_);

  gemm256_k<0><<<dim3((QKVN / 256) * (MROWS / 256)), 512, 0, stream>>>(
      Xb, WaT, b_attn, nullptr, Qb, Kb, Vt, MROWS, QKVN, HIDDEN_, QKVN / 256);

  attn_k<<<16 * 64, 512, 0, stream>>>(Qb, Kb, Vt, ctx);

  gemm256_k<1><<<dim3((HIDDEN_ / 256) * (MROWS / 256)), 512, 0, stream>>>(
      ctx, WpT, b_proj, out, nullptr, nullptr, nullptr, MROWS, HIDDEN_, HIDDEN_, HIDDEN_ / 256);
}